// Round 9
// baseline (488.181 us; speedup 1.0000x reference)
//
#include <hip/hip_runtime.h>
#include <hip/hip_bf16.h>

typedef short bf16x8 __attribute__((ext_vector_type(8)));
typedef float f32x4 __attribute__((ext_vector_type(4)));

#define CHUNK 4096

// ---------------- helpers ----------------
__device__ __forceinline__ float wred_sum(float v) {
  #pragma unroll
  for (int off = 32; off > 0; off >>= 1)
    v += __shfl_xor(v, off, 64);
  return v;
}
__device__ __forceinline__ float b2f(unsigned short u) {
  union { unsigned int i; float f; } x;
  x.i = ((unsigned int)u) << 16;
  return x.f;
}
__device__ __forceinline__ unsigned short f2bu(float f) {
  __hip_bfloat16 b = __float2bfloat16(f);
  return *(unsigned short*)&b;
}
// Runtime-dtype float load: is16 ? bf16 : fp32. Wave-uniform flag.
__device__ __forceinline__ float ldf(const void* p, long long i, int is16) {
  return is16 ? __bfloat162float(((const __hip_bfloat16*)p)[i])
              : ((const float*)p)[i];
}
// edge_index may arrive as int32 or int64 (reference declares int64).
__device__ __forceinline__ int edge_at(const int* e, long long idx, int is64) {
  return is64 ? (int)((const long long*)e)[idx] : e[idx];
}
// fp32 -> bf16x8 fragment load (8 consecutive channels)
__device__ __forceinline__ bf16x8 ld_frag_f32(const float* p) {
  float4 u = *(const float4*)p;
  float4 v = *(const float4*)(p + 4);
  bf16x8 r;
  r[0] = (short)f2bu(u.x); r[1] = (short)f2bu(u.y);
  r[2] = (short)f2bu(u.z); r[3] = (short)f2bu(u.w);
  r[4] = (short)f2bu(v.x); r[5] = (short)f2bu(v.y);
  r[6] = (short)f2bu(v.z); r[7] = (short)f2bu(v.w);
  return r;
}

// flag[0] = edge-is-int64, flag[1] = floats-are-bf16
__global__ void detect_kernel(const int* __restrict__ edge, int n_edge_check,
                              const unsigned int* __restrict__ xw, int n_x_check,
                              int* __restrict__ flag) {
  __shared__ int s_nz, s_cnt, s_tot;
  int tid = threadIdx.x;
  if (tid == 0) { s_nz = 0; s_cnt = 0; s_tot = 0; }
  __syncthreads();
  int nz = 0;
  for (int k = tid; k < n_edge_check; k += 256)
    if (edge[2 * k + 1] != 0) nz = 1;
  if (nz) atomicOr(&s_nz, 1);
  // bf16-packed words have bits 14..7 = exponent ~[100,150] for N(0,1) data.
  int c = 0, t = 0;
  for (int k = tid; k < n_x_check; k += 256) {
    unsigned int w = xw[k];
    if (w == 0u) continue;
    t++;
    unsigned int e = (w >> 7) & 0xFFu;
    if (e >= 100u && e <= 150u) c++;
  }
  atomicAdd(&s_cnt, c);
  atomicAdd(&s_tot, t);
  __syncthreads();
  if (tid == 0) {
    flag[0] = (s_nz == 0) ? 1 : 0;
    flag[1] = (s_cnt * 10 > s_tot * 6) ? 1 : 0;
  }
}

// ---------------- CSR build: 2-level bucket sort ----------------
// Bucket b covers dst in [256b, 256b+256). NB = ceil(N/256) <= 1024.
// Payload pack: (dst & 255) << 24 | src   (requires N < 2^24).

__global__ __launch_bounds__(256) void bucket_count_kernel(
    const int* __restrict__ edge, int E, int N, const int* __restrict__ flag,
    int* __restrict__ bcnt, int NB) {
  __shared__ int cnt[1024];
  int tid = threadIdx.x;
  long long base = (long long)blockIdx.x * CHUNK;
  long long total = (long long)E + N;
  for (int b = tid; b < NB; b += 256) cnt[b] = 0;
  __syncthreads();
  int is64 = flag[0];
  #pragma unroll
  for (int j = 0; j < 16; j++) {
    long long i = base + j * 256 + tid;
    if (i < total) {
      int d = (i < E) ? edge_at(edge, (long long)E + i, is64) : (int)(i - E);
      d = min(max(d, 0), N - 1);
      atomicAdd(&cnt[d >> 8], 1);
    }
  }
  __syncthreads();
  for (int b = tid; b < NB; b += 256)
    if (cnt[b]) atomicAdd(&bcnt[b], cnt[b]);
}

__global__ void bucket_scan_kernel(const int* __restrict__ bcnt, int NB,
                                   int* __restrict__ bbase, int* __restrict__ bcursor) {
  __shared__ int s[256];
  __shared__ int rbase;
  int tid = threadIdx.x;
  if (tid == 0) rbase = 0;
  __syncthreads();
  for (int c0 = 0; c0 < NB; c0 += 256) {
    int idx = c0 + tid;
    int v = (idx < NB) ? bcnt[idx] : 0;
    s[tid] = v;
    __syncthreads();
    for (int off = 1; off < 256; off <<= 1) {
      int t = (tid >= off) ? s[tid - off] : 0;
      __syncthreads();
      s[tid] += t;
      __syncthreads();
    }
    int mb = rbase;
    if (idx < NB) {
      int exc = mb + s[tid] - v;
      bbase[idx] = exc;
      bcursor[idx] = exc;
    }
    __syncthreads();
    if (tid == 0) rbase = mb + s[255];
    __syncthreads();
  }
  if (tid == 0) bbase[NB] = rbase;
}

__global__ __launch_bounds__(256) void partition_kernel(
    const int* __restrict__ edge, int E, int N, const int* __restrict__ flag,
    int* __restrict__ bcursor, unsigned int* __restrict__ part, int NB) {
  __shared__ int cnt[1024];
  __shared__ int loff[1025];
  __shared__ int gpos[1024];
  __shared__ int lcur[1024];
  __shared__ unsigned int staged[CHUNK];
  __shared__ int s[256];
  __shared__ int rbase;
  int tid = threadIdx.x;
  long long base = (long long)blockIdx.x * CHUNK;
  long long total = (long long)E + N;
  int here = (int)min((long long)CHUNK, total - base);
  for (int b = tid; b < NB; b += 256) cnt[b] = 0;
  if (tid == 0) rbase = 0;
  __syncthreads();
  int is64 = flag[0];
  int myb[16];
  unsigned int myp[16];
  #pragma unroll
  for (int j = 0; j < 16; j++) {
    long long i = base + j * 256 + tid;
    myb[j] = -1;
    if (i < total) {
      int d, sv;
      if (i < E) {
        sv = edge_at(edge, i, is64);
        d = edge_at(edge, (long long)E + i, is64);
      } else {
        sv = d = (int)(i - E);
      }
      d = min(max(d, 0), N - 1);
      sv = min(max(sv, 0), N - 1);
      myb[j] = d >> 8;
      myp[j] = ((unsigned int)(d & 255) << 24) | (unsigned int)sv;
      atomicAdd(&cnt[myb[j]], 1);
    }
  }
  __syncthreads();
  for (int c0 = 0; c0 < NB; c0 += 256) {
    int idx = c0 + tid;
    int v = (idx < NB) ? cnt[idx] : 0;
    s[tid] = v;
    __syncthreads();
    for (int off = 1; off < 256; off <<= 1) {
      int t = (tid >= off) ? s[tid - off] : 0;
      __syncthreads();
      s[tid] += t;
      __syncthreads();
    }
    int mb = rbase;
    if (idx < NB) loff[idx] = mb + s[tid] - v;
    __syncthreads();
    if (tid == 0) rbase = mb + s[255];
    __syncthreads();
  }
  if (tid == 0) loff[NB] = rbase;  // == here
  __syncthreads();
  for (int b = tid; b < NB; b += 256) {
    int c = cnt[b];
    gpos[b] = c ? atomicAdd(&bcursor[b], c) : 0;
    lcur[b] = loff[b];
  }
  __syncthreads();
  #pragma unroll
  for (int j = 0; j < 16; j++) {
    if (myb[j] >= 0) {
      int slot = atomicAdd(&lcur[myb[j]], 1);
      staged[slot] = myp[j];
    }
  }
  __syncthreads();
  for (int i = tid; i < here; i += 256) {
    int lo = 0, hi = NB;
    while (hi - lo > 1) {
      int mid = (lo + hi) >> 1;
      if (loff[mid] <= i) lo = mid; else hi = mid;
    }
    part[gpos[lo] + (i - loff[lo])] = staged[i];
  }
}

__global__ __launch_bounds__(256) void bucket_sort_kernel(
    const unsigned int* __restrict__ part, const int* __restrict__ bbase,
    int N, int total, int* __restrict__ indptr, int* __restrict__ ssrc) {
  __shared__ int hist[256], cur[256];
  __shared__ int s[256];
  int tid = threadIdx.x;
  int b = blockIdx.x;
  int begin = bbase[b], end = bbase[b + 1];
  hist[tid] = 0;
  __syncthreads();
  for (int i = begin + tid; i < end; i += 256)
    atomicAdd(&hist[part[i] >> 24], 1);
  __syncthreads();
  int v = hist[tid];
  s[tid] = v;
  __syncthreads();
  for (int off = 1; off < 256; off <<= 1) {
    int t = (tid >= off) ? s[tid - off] : 0;
    __syncthreads();
    s[tid] += t;
    __syncthreads();
  }
  int exc = s[tid] - v;
  cur[tid] = exc;
  int d = b * 256 + tid;
  if (d < N) indptr[d] = begin + exc;
  if (b == 0 && tid == 0) indptr[N] = total;
  __syncthreads();
  for (int i = begin + tid; i < end; i += 256) {
    unsigned int p = part[i];
    int pos = begin + atomicAdd(&cur[p >> 24], 1);
    ssrc[pos] = (int)(p & 0xFFFFFFu);
  }
}

// ---------------- weight transpose: B[K x Nout] -> BtT[Noutpad x K] bf16 ----------------
__global__ void transpose_kernel(const void* __restrict__ B, __hip_bfloat16* __restrict__ BtT,
                                 int K, int Nout, int Noutpad, const int* __restrict__ dflag) {
  int idx = blockIdx.x * 256 + threadIdx.x;
  if (idx >= Noutpad * K) return;
  int n = idx / K, k = idx - n * K;
  float v = (n < Nout) ? ldf(B, (long long)k * Nout + n, dflag[1]) : 0.f;
  BtT[idx] = __float2bfloat16(v);
}

// ---------------- MFMA bf16 GEMM + fused att epilogue ----------------
// block = 256 thr = 4 waves; tile 64x64; wave w owns rows [w*16, w*16+16).
// A: AFLAGGED ? (runtime bf16-or-fp32, converted in-register) : always bf16.
// A rows clamped to M-1 (out-of-range C rows are never stored).
// BtT [Noutpad x K] bf16, L2-resident, fragments direct from global.
// mfma_f32_16x16x32_bf16 layouts [learn_hip m89/m91]:
//   A[m][k]: m = lane&15, k = (lane>>4)*8 + j ;  B-op from BtT rows likewise.
//   C/D: col = lane&15, row = (lane>>4)*4 + reg
// Epilogue computes a_src/a_dst = C-row . att (16-lane butterfly).
template <bool AFLAGGED>
__global__ __launch_bounds__(256) void mfma_gemm_kernel(
    const void* __restrict__ Av, const __hip_bfloat16* __restrict__ BtT,
    __hip_bfloat16* __restrict__ Cb,
    const void* __restrict__ attS, const void* __restrict__ attD,
    float* __restrict__ aS, float* __restrict__ aD, int att_stride,
    int M, int Nout, int K, const int* __restrict__ dflag) {
  int f16 = dflag[1];
  int a16 = AFLAGGED ? f16 : 1;
  int tid = threadIdx.x;
  int w = tid >> 6, l = tid & 63;
  int m_lane = l & 15, q = l >> 4;
  int row0 = blockIdx.x * 64, col0 = blockIdx.y * 64;
  long long arow = min(row0 + w * 16 + m_lane, M - 1);
  const __hip_bfloat16* Brow = BtT + (long long)(col0 + m_lane) * K + q * 8;
  f32x4 acc[4] = {};
  if (a16) {
    const __hip_bfloat16* Ap = (const __hip_bfloat16*)Av + arow * K + q * 8;
    #pragma unroll 4
    for (int k0 = 0; k0 < K; k0 += 32) {
      bf16x8 af = *(const bf16x8*)(Ap + k0);
      #pragma unroll
      for (int t = 0; t < 4; t++) {
        bf16x8 bf = *(const bf16x8*)(Brow + (long long)t * 16 * K + k0);
        acc[t] = __builtin_amdgcn_mfma_f32_16x16x32_bf16(af, bf, acc[t], 0, 0, 0);
      }
    }
  } else {
    const float* Ap = (const float*)Av + arow * K + q * 8;
    #pragma unroll 4
    for (int k0 = 0; k0 < K; k0 += 32) {
      bf16x8 af = ld_frag_f32(Ap + k0);
      #pragma unroll
      for (int t = 0; t < 4; t++) {
        bf16x8 bf = *(const bf16x8*)(Brow + (long long)t * 16 * K + k0);
        acc[t] = __builtin_amdgcn_mfma_f32_16x16x32_bf16(af, bf, acc[t], 0, 0, 0);
      }
    }
  }
  #pragma unroll
  for (int r = 0; r < 4; r++) {
    int gr = row0 + w * 16 + q * 4 + r;
    float ps = 0.f, pd = 0.f;
    #pragma unroll
    for (int t = 0; t < 4; t++) {
      int gc = col0 + t * 16 + m_lane;
      float v = acc[t][r];
      if (gc < Nout) {
        ps += v * ldf(attS, gc, f16);
        pd += v * ldf(attD, gc, f16);
        if (gr < M) Cb[(long long)gr * Nout + gc] = __float2bfloat16(v);
      }
    }
    #pragma unroll
    for (int off = 1; off < 16; off <<= 1) {
      ps += __shfl_xor(ps, off, 64);
      pd += __shfl_xor(pd, off, 64);
    }
    if (m_lane == 0 && gr < M) {
      aS[(long long)gr * att_stride + blockIdx.y] = ps;
      aD[(long long)gr * att_stride + blockIdx.y] = pd;
    }
  }
}

// ---------------- layer-1 single-pass softmax + aggregate + bias + ELU ----------------
// TWO waves per dst (block = 4 waves = 2 dsts): wave `sub` of a pair takes
// alternate 32-edge chunks -> 64 loads in flight per dst, halved serial chain,
// halved tail imbalance. Partials (den, acc0..3) combine via LDS.
// Lane l: head q=l>>4, owns channels 4l..4l+3 (8B load/edge). Single-pass
// softmax (no max-shift; |logit|<~20 safe in fp32), divide at end.
__global__ __launch_bounds__(256) void aggregate1_kernel(
    const int* __restrict__ indptr, const int* __restrict__ ssrc,
    const __hip_bfloat16* __restrict__ h1b, const float* __restrict__ a_src,
    const float* __restrict__ a_dst, const void* __restrict__ b1,
    __hip_bfloat16* __restrict__ h2b, int N, const int* __restrict__ dflag) {
  __shared__ float comb[2][5][64];
  int f16 = dflag[1];
  int pair = threadIdx.x >> 7;        // which dst of the block
  int sub = (threadIdx.x >> 6) & 1;   // wave within the pair
  int l = threadIdx.x & 63;
  int d = blockIdx.x * 2 + pair;
  bool valid = d < N;
  int q = l >> 4;
  int e16 = l & 15;
  int base = l & 48;
  float den = 0.f;
  float acc0 = 0.f, acc1 = 0.f, acc2 = 0.f, acc3 = 0.f;
  int begin = 0, end = 0;
  float adst = 0.f;
  if (valid) {
    begin = indptr[d];
    end = indptr[d + 1];
    adst = a_dst[d * 4 + q];
    int s0 = ssrc[begin];
    for (int c = begin + sub * 32; c < end; c += 64) {
      int cnt = end - c;
      int sj0 = s0, sj1 = s0;
      float wj0 = 0.f, wj1 = 0.f;
      if (e16 < cnt) {
        sj0 = ssrc[c + e16];
        float e = a_src[sj0 * 4 + q] + adst;
        e = (e > 0.f) ? e : 0.2f * e;
        wj0 = __expf(e);
      }
      if (e16 + 16 < cnt) {
        sj1 = ssrc[c + e16 + 16];
        float e = a_src[sj1 * 4 + q] + adst;
        e = (e > 0.f) ? e : 0.2f * e;
        wj1 = __expf(e);
      }
      den += wj0 + wj1;
      #pragma unroll
      for (int j = 0; j < 16; j++) {
        int s = __shfl(sj0, base + j, 64);
        float wt = __shfl(wj0, base + j, 64);
        ushort4 hv = *(const ushort4*)((const unsigned short*)h1b +
                                       (long long)s * 256 + 4 * l);
        acc0 += wt * b2f(hv.x);
        acc1 += wt * b2f(hv.y);
        acc2 += wt * b2f(hv.z);
        acc3 += wt * b2f(hv.w);
      }
      #pragma unroll
      for (int j = 0; j < 16; j++) {
        int s = __shfl(sj1, base + j, 64);
        float wt = __shfl(wj1, base + j, 64);
        ushort4 hv = *(const ushort4*)((const unsigned short*)h1b +
                                       (long long)s * 256 + 4 * l);
        acc0 += wt * b2f(hv.x);
        acc1 += wt * b2f(hv.y);
        acc2 += wt * b2f(hv.z);
        acc3 += wt * b2f(hv.w);
      }
    }
  }
  // combine the pair's two waves through LDS
  if (sub == 1) {
    comb[pair][0][l] = den;
    comb[pair][1][l] = acc0;
    comb[pair][2][l] = acc1;
    comb[pair][3][l] = acc2;
    comb[pair][4][l] = acc3;
  }
  __syncthreads();
  if (valid && sub == 0) {
    den += comb[pair][0][l];
    acc0 += comb[pair][1][l];
    acc1 += comb[pair][2][l];
    acc2 += comb[pair][3][l];
    acc3 += comb[pair][4][l];
    #pragma unroll
    for (int off = 1; off < 16; off <<= 1)
      den += __shfl_xor(den, off, 64);
    float inv = 1.f / den;  // >= exp(self-loop) > 0
    float v0 = acc0 * inv + ldf(b1, 4 * l + 0, f16);
    float v1 = acc1 * inv + ldf(b1, 4 * l + 1, f16);
    float v2 = acc2 * inv + ldf(b1, 4 * l + 2, f16);
    float v3 = acc3 * inv + ldf(b1, 4 * l + 3, f16);
    v0 = (v0 > 0.f) ? v0 : (__expf(v0) - 1.f);
    v1 = (v1 > 0.f) ? v1 : (__expf(v1) - 1.f);
    v2 = (v2 > 0.f) ? v2 : (__expf(v2) - 1.f);
    v3 = (v3 > 0.f) ? v3 : (__expf(v3) - 1.f);
    ushort4 o;
    o.x = f2bu(v0); o.y = f2bu(v1); o.z = f2bu(v2); o.w = f2bu(v3);
    *(ushort4*)((unsigned short*)h2b + (long long)d * 256 + 4 * l) = o;
  }
}

// ---------------- layer-2 single-pass softmax + aggregate + bias -> out ----------------
// TWO waves per dst, alternate 64-edge chunks, LDS combine. C=40 bf16 = 20
// pairs; within a wave lanes split 3 edges x 20 channel-pairs.
__global__ __launch_bounds__(256) void aggregate2_kernel(
    const int* __restrict__ indptr, const int* __restrict__ ssrc,
    const __hip_bfloat16* __restrict__ gb, const float* __restrict__ a_src,
    const float* __restrict__ a_dst, const void* __restrict__ b2,
    void* __restrict__ out, int N, int C, const int* __restrict__ dflag) {
  __shared__ float comb[2][3][64];
  int f16 = dflag[1];
  int pair = threadIdx.x >> 7;
  int sub = (threadIdx.x >> 6) & 1;
  int l = threadIdx.x & 63;
  int d = blockIdx.x * 2 + pair;
  bool valid = d < N;
  int e_off = l / 20;           // 0,1,2 active; lanes 60-63 idle in gather
  int pr = l - e_off * 20;      // channel pair 0..19
  bool active = (e_off < 3);
  float den = 0.f;
  float acc0 = 0.f, acc1 = 0.f;
  if (valid) {
    int begin = indptr[d], end = indptr[d + 1];
    float adst = a_dst[d];
    int s0 = ssrc[begin];
    for (int c = begin + sub * 64; c < end; c += 128) {
      int cnt = min(64, end - c);
      int sj = s0;
      float wj = 0.f;
      if (l < cnt) {
        sj = ssrc[c + l];
        float e = a_src[sj] + adst;
        e = (e > 0.f) ? e : 0.2f * e;
        wj = __expf(e);
      }
      den += wj;
      #pragma unroll 4
      for (int j = 0; j < cnt; j += 3) {
        int idx = j + e_off;
        int s = __shfl(sj, idx & 63, 64);
        float wt = __shfl(wj, idx & 63, 64);
        if (!active || idx >= cnt) wt = 0.f;
        ushort2 gv = *(const ushort2*)((const unsigned short*)gb +
                                       (long long)s * C + 2 * pr);
        acc0 += wt * b2f(gv.x);
        acc1 += wt * b2f(gv.y);
      }
    }
  }
  if (sub == 1) {
    comb[pair][0][l] = den;
    comb[pair][1][l] = acc0;
    comb[pair][2][l] = acc1;
  }
  __syncthreads();
  if (valid && sub == 0) {
    den += comb[pair][0][l];
    acc0 += comb[pair][1][l];
    acc1 += comb[pair][2][l];
    den = wred_sum(den);
    float inv = 1.f / den;
    float r0 = acc0 + __shfl(acc0, (l + 20) & 63, 64) + __shfl(acc0, (l + 40) & 63, 64);
    float r1 = acc1 + __shfl(acc1, (l + 20) & 63, 64) + __shfl(acc1, (l + 40) & 63, 64);
    if (l < 20) {
      float v0 = r0 * inv + ldf(b2, 2 * l + 0, f16);
      float v1 = r1 * inv + ldf(b2, 2 * l + 1, f16);
      long long o = (long long)d * C + 2 * l;
      if (f16) {
        ushort2 ov;
        ov.x = f2bu(v0); ov.y = f2bu(v1);
        *(ushort2*)((unsigned short*)out + o) = ov;
      } else {
        float2 ov;
        ov.x = v0; ov.y = v1;
        *(float2*)((float*)out + o) = ov;
      }
    }
  }
}

extern "C" void kernel_launch(void* const* d_in, const int* in_sizes, int n_in,
                              void* d_out, int out_size, void* d_ws, size_t ws_size,
                              hipStream_t stream) {
  const void* x   = d_in[0];
  const int* edge = (const int*)d_in[1];
  const void* W1  = d_in[2];
  const void* as1 = d_in[3];
  const void* ad1 = d_in[4];
  const void* b1  = d_in[5];
  const void* W2  = d_in[6];
  const void* as2 = d_in[7];
  const void* ad2 = d_in[8];
  const void* b2  = d_in[9];

  const int F  = 256;                 // F_in
  const int HC = 256;                 // H*C1
  const int N  = in_sizes[0] / F;     // 50000
  const int E  = in_sizes[1] / 2;     // 1600000
  const int C2 = in_sizes[9];         // 40
  const int C2p = 64;                 // padded cols for layer-2 B^T
  const int total = E + N;
  const int NB = (N + 255) / 256;     // buckets (196)
  const int Mpad = ((N + 63) / 64) * 64;

  char* p = (char*)d_ws;
  auto alloc = [&](size_t bytes) -> void* {
    void* r = (void*)p;
    p += (bytes + 255) & ~(size_t)255;
    return r;
  };
  __hip_bfloat16* h1b = (__hip_bfloat16*)alloc((size_t)Mpad * HC * 2);
  __hip_bfloat16* h2b = (__hip_bfloat16*)alloc((size_t)Mpad * HC * 2);
  __hip_bfloat16* gb  = (__hip_bfloat16*)alloc((size_t)Mpad * C2 * 2);
  __hip_bfloat16* Wt1 = (__hip_bfloat16*)alloc((size_t)HC * F * 2);
  __hip_bfloat16* Wt2 = (__hip_bfloat16*)alloc((size_t)C2p * HC * 2);
  float* a_src1 = (float*)alloc((size_t)N * 4 * 4);
  float* a_dst1 = (float*)alloc((size_t)N * 4 * 4);
  float* a_src2 = (float*)alloc((size_t)N * 4);
  float* a_dst2 = (float*)alloc((size_t)N * 4);
  unsigned int* part = (unsigned int*)alloc((size_t)total * 4);
  int* bcnt     = (int*)alloc((size_t)(NB + 1) * 4);
  int* bbase    = (int*)alloc((size_t)(NB + 1) * 4);
  int* bcursor  = (int*)alloc((size_t)NB * 4);
  int* indptr   = (int*)alloc((size_t)(N + 1) * 4);
  int* ssrc     = (int*)alloc((size_t)total * 4);
  int* flag     = (int*)alloc(256);

  // ---- detection + CSR build (2-level bucket sort) ----
  hipMemsetAsync(bcnt, 0, (size_t)(NB + 1) * 4, stream);
  detect_kernel<<<1, 256, 0, stream>>>(edge, E < 2048 ? E : 2048,
                                       (const unsigned int*)x, 4096, flag);
  int nch = (total + CHUNK - 1) / CHUNK;
  bucket_count_kernel<<<nch, 256, 0, stream>>>(edge, E, N, flag, bcnt, NB);
  bucket_scan_kernel<<<1, 256, 0, stream>>>(bcnt, NB, bbase, bcursor);
  partition_kernel<<<nch, 256, 0, stream>>>(edge, E, N, flag, bcursor, part, NB);
  bucket_sort_kernel<<<NB, 256, 0, stream>>>(part, bbase, N, total, indptr, ssrc);

  // ---- weight transposes ----
  transpose_kernel<<<(HC * F + 255) / 256, 256, 0, stream>>>(W1, Wt1, F, HC, HC, flag);
  transpose_kernel<<<(C2p * HC + 255) / 256, 256, 0, stream>>>(W2, Wt2, HC, C2, C2p, flag);

  // ---- layer 1: gemm (+fused att, direct A read) -> aggregate ----
  dim3 g1(Mpad / 64, HC / 64);
  mfma_gemm_kernel<true><<<g1, 256, 0, stream>>>(x, Wt1, h1b,
                                                 as1, ad1, a_src1, a_dst1, 4,
                                                 N, HC, F, flag);
  aggregate1_kernel<<<(N + 1) / 2, 256, 0, stream>>>(indptr, ssrc, h1b, a_src1, a_dst1,
                                                     b1, h2b, N, flag);

  // ---- layer 2: gemm (+fused att) -> aggregate ----
  dim3 g2(Mpad / 64, 1);
  mfma_gemm_kernel<false><<<g2, 256, 0, stream>>>(h2b, Wt2, gb,
                                                  as2, ad2, a_src2, a_dst2, 1,
                                                  N, C2, HC, flag);
  aggregate2_kernel<<<(N + 1) / 2, 256, 0, stream>>>(indptr, ssrc, gb, a_src2, a_dst2,
                                                     b2, d_out, N, C2, flag);
}

// Round 10
// 460.957 us; speedup vs baseline: 1.0591x; 1.0591x over previous
//
#include <hip/hip_runtime.h>
#include <hip/hip_bf16.h>

typedef short bf16x8 __attribute__((ext_vector_type(8)));
typedef float f32x4 __attribute__((ext_vector_type(4)));

#define CHUNK 4096

// ---------------- helpers ----------------
__device__ __forceinline__ float wred_sum(float v) {
  #pragma unroll
  for (int off = 32; off > 0; off >>= 1)
    v += __shfl_xor(v, off, 64);
  return v;
}
__device__ __forceinline__ float b2f(unsigned short u) {
  union { unsigned int i; float f; } x;
  x.i = ((unsigned int)u) << 16;
  return x.f;
}
__device__ __forceinline__ unsigned short f2bu(float f) {
  __hip_bfloat16 b = __float2bfloat16(f);
  return *(unsigned short*)&b;
}
// Runtime-dtype float load: is16 ? bf16 : fp32. Wave-uniform flag.
__device__ __forceinline__ float ldf(const void* p, long long i, int is16) {
  return is16 ? __bfloat162float(((const __hip_bfloat16*)p)[i])
              : ((const float*)p)[i];
}
// edge_index may arrive as int32 or int64 (reference declares int64).
__device__ __forceinline__ int edge_at(const int* e, long long idx, int is64) {
  return is64 ? (int)((const long long*)e)[idx] : e[idx];
}
// fp32 -> bf16x8 fragment load (8 consecutive channels)
__device__ __forceinline__ bf16x8 ld_frag_f32(const float* p) {
  float4 u = *(const float4*)p;
  float4 v = *(const float4*)(p + 4);
  bf16x8 r;
  r[0] = (short)f2bu(u.x); r[1] = (short)f2bu(u.y);
  r[2] = (short)f2bu(u.z); r[3] = (short)f2bu(u.w);
  r[4] = (short)f2bu(v.x); r[5] = (short)f2bu(v.y);
  r[6] = (short)f2bu(v.z); r[7] = (short)f2bu(v.w);
  return r;
}

// flag[0] = edge-is-int64, flag[1] = floats-are-bf16
__global__ void detect_kernel(const int* __restrict__ edge, int n_edge_check,
                              const unsigned int* __restrict__ xw, int n_x_check,
                              int* __restrict__ flag) {
  __shared__ int s_nz, s_cnt, s_tot;
  int tid = threadIdx.x;
  if (tid == 0) { s_nz = 0; s_cnt = 0; s_tot = 0; }
  __syncthreads();
  int nz = 0;
  for (int k = tid; k < n_edge_check; k += 256)
    if (edge[2 * k + 1] != 0) nz = 1;
  if (nz) atomicOr(&s_nz, 1);
  // bf16-packed words have bits 14..7 = exponent ~[100,150] for N(0,1) data.
  int c = 0, t = 0;
  for (int k = tid; k < n_x_check; k += 256) {
    unsigned int w = xw[k];
    if (w == 0u) continue;
    t++;
    unsigned int e = (w >> 7) & 0xFFu;
    if (e >= 100u && e <= 150u) c++;
  }
  atomicAdd(&s_cnt, c);
  atomicAdd(&s_tot, t);
  __syncthreads();
  if (tid == 0) {
    flag[0] = (s_nz == 0) ? 1 : 0;
    flag[1] = (s_cnt * 10 > s_tot * 6) ? 1 : 0;
  }
}

// ---------------- CSR build: 2-level bucket sort ----------------
// Bucket b covers dst in [256b, 256b+256). NB = ceil(N/256) <= 1024.
// Payload pack: (dst & 255) << 24 | src   (requires N < 2^24).

__global__ __launch_bounds__(256) void bucket_count_kernel(
    const int* __restrict__ edge, int E, int N, const int* __restrict__ flag,
    int* __restrict__ bcnt, int NB) {
  __shared__ int cnt[1024];
  int tid = threadIdx.x;
  long long base = (long long)blockIdx.x * CHUNK;
  long long total = (long long)E + N;
  for (int b = tid; b < NB; b += 256) cnt[b] = 0;
  __syncthreads();
  int is64 = flag[0];
  #pragma unroll
  for (int j = 0; j < 16; j++) {
    long long i = base + j * 256 + tid;
    if (i < total) {
      int d = (i < E) ? edge_at(edge, (long long)E + i, is64) : (int)(i - E);
      d = min(max(d, 0), N - 1);
      atomicAdd(&cnt[d >> 8], 1);
    }
  }
  __syncthreads();
  for (int b = tid; b < NB; b += 256)
    if (cnt[b]) atomicAdd(&bcnt[b], cnt[b]);
}

__global__ void bucket_scan_kernel(const int* __restrict__ bcnt, int NB,
                                   int* __restrict__ bbase, int* __restrict__ bcursor) {
  __shared__ int s[256];
  __shared__ int rbase;
  int tid = threadIdx.x;
  if (tid == 0) rbase = 0;
  __syncthreads();
  for (int c0 = 0; c0 < NB; c0 += 256) {
    int idx = c0 + tid;
    int v = (idx < NB) ? bcnt[idx] : 0;
    s[tid] = v;
    __syncthreads();
    for (int off = 1; off < 256; off <<= 1) {
      int t = (tid >= off) ? s[tid - off] : 0;
      __syncthreads();
      s[tid] += t;
      __syncthreads();
    }
    int mb = rbase;
    if (idx < NB) {
      int exc = mb + s[tid] - v;
      bbase[idx] = exc;
      bcursor[idx] = exc;
    }
    __syncthreads();
    if (tid == 0) rbase = mb + s[255];
    __syncthreads();
  }
  if (tid == 0) bbase[NB] = rbase;
}

__global__ __launch_bounds__(256) void partition_kernel(
    const int* __restrict__ edge, int E, int N, const int* __restrict__ flag,
    int* __restrict__ bcursor, unsigned int* __restrict__ part, int NB) {
  __shared__ int cnt[1024];
  __shared__ int loff[1025];
  __shared__ int gpos[1024];
  __shared__ int lcur[1024];
  __shared__ unsigned int staged[CHUNK];
  __shared__ int s[256];
  __shared__ int rbase;
  int tid = threadIdx.x;
  long long base = (long long)blockIdx.x * CHUNK;
  long long total = (long long)E + N;
  int here = (int)min((long long)CHUNK, total - base);
  for (int b = tid; b < NB; b += 256) cnt[b] = 0;
  if (tid == 0) rbase = 0;
  __syncthreads();
  int is64 = flag[0];
  int myb[16];
  unsigned int myp[16];
  #pragma unroll
  for (int j = 0; j < 16; j++) {
    long long i = base + j * 256 + tid;
    myb[j] = -1;
    if (i < total) {
      int d, sv;
      if (i < E) {
        sv = edge_at(edge, i, is64);
        d = edge_at(edge, (long long)E + i, is64);
      } else {
        sv = d = (int)(i - E);
      }
      d = min(max(d, 0), N - 1);
      sv = min(max(sv, 0), N - 1);
      myb[j] = d >> 8;
      myp[j] = ((unsigned int)(d & 255) << 24) | (unsigned int)sv;
      atomicAdd(&cnt[myb[j]], 1);
    }
  }
  __syncthreads();
  for (int c0 = 0; c0 < NB; c0 += 256) {
    int idx = c0 + tid;
    int v = (idx < NB) ? cnt[idx] : 0;
    s[tid] = v;
    __syncthreads();
    for (int off = 1; off < 256; off <<= 1) {
      int t = (tid >= off) ? s[tid - off] : 0;
      __syncthreads();
      s[tid] += t;
      __syncthreads();
    }
    int mb = rbase;
    if (idx < NB) loff[idx] = mb + s[tid] - v;
    __syncthreads();
    if (tid == 0) rbase = mb + s[255];
    __syncthreads();
  }
  if (tid == 0) loff[NB] = rbase;  // == here
  __syncthreads();
  for (int b = tid; b < NB; b += 256) {
    int c = cnt[b];
    gpos[b] = c ? atomicAdd(&bcursor[b], c) : 0;
    lcur[b] = loff[b];
  }
  __syncthreads();
  #pragma unroll
  for (int j = 0; j < 16; j++) {
    if (myb[j] >= 0) {
      int slot = atomicAdd(&lcur[myb[j]], 1);
      staged[slot] = myp[j];
    }
  }
  __syncthreads();
  for (int i = tid; i < here; i += 256) {
    int lo = 0, hi = NB;
    while (hi - lo > 1) {
      int mid = (lo + hi) >> 1;
      if (loff[mid] <= i) lo = mid; else hi = mid;
    }
    part[gpos[lo] + (i - loff[lo])] = staged[i];
  }
}

__global__ __launch_bounds__(256) void bucket_sort_kernel(
    const unsigned int* __restrict__ part, const int* __restrict__ bbase,
    int N, int total, int* __restrict__ indptr, int* __restrict__ ssrc) {
  __shared__ int hist[256], cur[256];
  __shared__ int s[256];
  int tid = threadIdx.x;
  int b = blockIdx.x;
  int begin = bbase[b], end = bbase[b + 1];
  hist[tid] = 0;
  __syncthreads();
  for (int i = begin + tid; i < end; i += 256)
    atomicAdd(&hist[part[i] >> 24], 1);
  __syncthreads();
  int v = hist[tid];
  s[tid] = v;
  __syncthreads();
  for (int off = 1; off < 256; off <<= 1) {
    int t = (tid >= off) ? s[tid - off] : 0;
    __syncthreads();
    s[tid] += t;
    __syncthreads();
  }
  int exc = s[tid] - v;
  cur[tid] = exc;
  int d = b * 256 + tid;
  if (d < N) indptr[d] = begin + exc;
  if (b == 0 && tid == 0) indptr[N] = total;
  __syncthreads();
  for (int i = begin + tid; i < end; i += 256) {
    unsigned int p = part[i];
    int pos = begin + atomicAdd(&cur[p >> 24], 1);
    ssrc[pos] = (int)(p & 0xFFFFFFu);
  }
}

// ---------------- fused weight transposes: W1 and W2 in one dispatch ----------------
// idx < HC*F: Wt1[n][k] = W1[k][n]  (K=F, Nout=HC)
// else:       Wt2[n][k] = W2[k][n]  (K=HC, Nout=C2, padded to C2p)
__global__ void transpose_both_kernel(const void* __restrict__ W1v,
                                      const void* __restrict__ W2v,
                                      __hip_bfloat16* __restrict__ Wt1,
                                      __hip_bfloat16* __restrict__ Wt2,
                                      int F, int HC, int C2, int C2p,
                                      const int* __restrict__ dflag) {
  int f16 = dflag[1];
  int idx = blockIdx.x * 256 + threadIdx.x;
  int n1 = HC * F;
  if (idx < n1) {
    int n = idx / F, k = idx - n * F;
    Wt1[idx] = __float2bfloat16(ldf(W1v, (long long)k * HC + n, f16));
  } else {
    int j = idx - n1;
    if (j >= C2p * HC) return;
    int n = j / HC, k = j - n * HC;
    float v = (n < C2) ? ldf(W2v, (long long)k * C2 + n, f16) : 0.f;
    Wt2[j] = __float2bfloat16(v);
  }
}

// ---------------- MFMA bf16 GEMM + fused att epilogue ----------------
// block = 256 thr = 4 waves; tile 64x64; wave w owns rows [w*16, w*16+16).
// A: AFLAGGED ? (runtime bf16-or-fp32, converted in-register) : always bf16.
// A rows clamped to M-1 (out-of-range C rows are never stored).
// BtT [Noutpad x K] bf16, L2-resident, fragments direct from global.
// mfma_f32_16x16x32_bf16 layouts [learn_hip m89/m91]:
//   A[m][k]: m = lane&15, k = (lane>>4)*8 + j ;  B-op from BtT rows likewise.
//   C/D: col = lane&15, row = (lane>>4)*4 + reg
// Epilogue computes a_src/a_dst = C-row . att (16-lane butterfly).
template <bool AFLAGGED>
__global__ __launch_bounds__(256) void mfma_gemm_kernel(
    const void* __restrict__ Av, const __hip_bfloat16* __restrict__ BtT,
    __hip_bfloat16* __restrict__ Cb,
    const void* __restrict__ attS, const void* __restrict__ attD,
    float* __restrict__ aS, float* __restrict__ aD, int att_stride,
    int M, int Nout, int K, const int* __restrict__ dflag) {
  int f16 = dflag[1];
  int a16 = AFLAGGED ? f16 : 1;
  int tid = threadIdx.x;
  int w = tid >> 6, l = tid & 63;
  int m_lane = l & 15, q = l >> 4;
  int row0 = blockIdx.x * 64, col0 = blockIdx.y * 64;
  long long arow = min(row0 + w * 16 + m_lane, M - 1);
  const __hip_bfloat16* Brow = BtT + (long long)(col0 + m_lane) * K + q * 8;
  f32x4 acc[4] = {};
  if (a16) {
    const __hip_bfloat16* Ap = (const __hip_bfloat16*)Av + arow * K + q * 8;
    #pragma unroll 4
    for (int k0 = 0; k0 < K; k0 += 32) {
      bf16x8 af = *(const bf16x8*)(Ap + k0);
      #pragma unroll
      for (int t = 0; t < 4; t++) {
        bf16x8 bf = *(const bf16x8*)(Brow + (long long)t * 16 * K + k0);
        acc[t] = __builtin_amdgcn_mfma_f32_16x16x32_bf16(af, bf, acc[t], 0, 0, 0);
      }
    }
  } else {
    const float* Ap = (const float*)Av + arow * K + q * 8;
    #pragma unroll 4
    for (int k0 = 0; k0 < K; k0 += 32) {
      bf16x8 af = ld_frag_f32(Ap + k0);
      #pragma unroll
      for (int t = 0; t < 4; t++) {
        bf16x8 bf = *(const bf16x8*)(Brow + (long long)t * 16 * K + k0);
        acc[t] = __builtin_amdgcn_mfma_f32_16x16x32_bf16(af, bf, acc[t], 0, 0, 0);
      }
    }
  }
  #pragma unroll
  for (int r = 0; r < 4; r++) {
    int gr = row0 + w * 16 + q * 4 + r;
    float ps = 0.f, pd = 0.f;
    #pragma unroll
    for (int t = 0; t < 4; t++) {
      int gc = col0 + t * 16 + m_lane;
      float v = acc[t][r];
      if (gc < Nout) {
        ps += v * ldf(attS, gc, f16);
        pd += v * ldf(attD, gc, f16);
        if (gr < M) Cb[(long long)gr * Nout + gc] = __float2bfloat16(v);
      }
    }
    #pragma unroll
    for (int off = 1; off < 16; off <<= 1) {
      ps += __shfl_xor(ps, off, 64);
      pd += __shfl_xor(pd, off, 64);
    }
    if (m_lane == 0 && gr < M) {
      aS[(long long)gr * att_stride + blockIdx.y] = ps;
      aD[(long long)gr * att_stride + blockIdx.y] = pd;
    }
  }
}

// ---------------- layer-1 single-pass softmax + aggregate + bias + ELU ----------------
// (round-7 form: 1 wave per dst — measured best; 2-wave LDS variant regressed.)
// Wave per dst node. Lane l: head q=l>>4, owns channels 4l..4l+3 (8B load/edge).
// Single pass (no max-shift; |logit|<~20 safe in fp32): unnormalized exp-weighted
// accumulate + denominator together; divide at end. 32-edge chunks.
// ssrc reads are non-temporal: the 6.6MB edge stream must not evict h1b from L2.
__global__ __launch_bounds__(256) void aggregate1_kernel(
    const int* __restrict__ indptr, const int* __restrict__ ssrc,
    const __hip_bfloat16* __restrict__ h1b, const float* __restrict__ a_src,
    const float* __restrict__ a_dst, const void* __restrict__ b1,
    __hip_bfloat16* __restrict__ h2b, int N, const int* __restrict__ dflag) {
  int f16 = dflag[1];
  int w = threadIdx.x >> 6, l = threadIdx.x & 63;
  int d = blockIdx.x * 4 + w;
  if (d >= N) return;
  int q = l >> 4;
  int e16 = l & 15;
  int base = l & 48;
  int begin = indptr[d], end = indptr[d + 1];
  float adst = a_dst[d * 4 + q];
  int s0 = __builtin_nontemporal_load(&ssrc[begin]);
  float den = 0.f;
  float acc0 = 0.f, acc1 = 0.f, acc2 = 0.f, acc3 = 0.f;
  for (int c = begin; c < end; c += 32) {
    int cnt = end - c;
    int sj0 = s0, sj1 = s0;
    float wj0 = 0.f, wj1 = 0.f;
    if (e16 < cnt) {
      sj0 = __builtin_nontemporal_load(&ssrc[c + e16]);
      float e = a_src[sj0 * 4 + q] + adst;
      e = (e > 0.f) ? e : 0.2f * e;
      wj0 = __expf(e);
    }
    if (e16 + 16 < cnt) {
      sj1 = __builtin_nontemporal_load(&ssrc[c + e16 + 16]);
      float e = a_src[sj1 * 4 + q] + adst;
      e = (e > 0.f) ? e : 0.2f * e;
      wj1 = __expf(e);
    }
    den += wj0 + wj1;
    #pragma unroll
    for (int j = 0; j < 16; j++) {
      int s = __shfl(sj0, base + j, 64);
      float wt = __shfl(wj0, base + j, 64);
      ushort4 hv = *(const ushort4*)((const unsigned short*)h1b +
                                     (long long)s * 256 + 4 * l);
      acc0 += wt * b2f(hv.x);
      acc1 += wt * b2f(hv.y);
      acc2 += wt * b2f(hv.z);
      acc3 += wt * b2f(hv.w);
    }
    #pragma unroll
    for (int j = 0; j < 16; j++) {
      int s = __shfl(sj1, base + j, 64);
      float wt = __shfl(wj1, base + j, 64);
      ushort4 hv = *(const ushort4*)((const unsigned short*)h1b +
                                     (long long)s * 256 + 4 * l);
      acc0 += wt * b2f(hv.x);
      acc1 += wt * b2f(hv.y);
      acc2 += wt * b2f(hv.z);
      acc3 += wt * b2f(hv.w);
    }
  }
  #pragma unroll
  for (int off = 1; off < 16; off <<= 1)
    den += __shfl_xor(den, off, 64);
  float inv = 1.f / den;
  float v0 = acc0 * inv + ldf(b1, 4 * l + 0, f16);
  float v1 = acc1 * inv + ldf(b1, 4 * l + 1, f16);
  float v2 = acc2 * inv + ldf(b1, 4 * l + 2, f16);
  float v3 = acc3 * inv + ldf(b1, 4 * l + 3, f16);
  v0 = (v0 > 0.f) ? v0 : (__expf(v0) - 1.f);
  v1 = (v1 > 0.f) ? v1 : (__expf(v1) - 1.f);
  v2 = (v2 > 0.f) ? v2 : (__expf(v2) - 1.f);
  v3 = (v3 > 0.f) ? v3 : (__expf(v3) - 1.f);
  ushort4 o;
  o.x = f2bu(v0); o.y = f2bu(v1); o.z = f2bu(v2); o.w = f2bu(v3);
  *(ushort4*)((unsigned short*)h2b + (long long)d * 256 + 4 * l) = o;
}

// ---------------- layer-2 single-pass softmax + aggregate + bias -> out ----------------
// (round-7 form: 1 wave per dst.) C=40 bf16 = 20 pairs; lanes split 3 edges x
// 20 channel-pairs. gb (4MB) is L2-resident; ssrc reads non-temporal.
__global__ __launch_bounds__(256) void aggregate2_kernel(
    const int* __restrict__ indptr, const int* __restrict__ ssrc,
    const __hip_bfloat16* __restrict__ gb, const float* __restrict__ a_src,
    const float* __restrict__ a_dst, const void* __restrict__ b2,
    void* __restrict__ out, int N, int C, const int* __restrict__ dflag) {
  int f16 = dflag[1];
  int w = threadIdx.x >> 6, l = threadIdx.x & 63;
  int d = blockIdx.x * 4 + w;
  if (d >= N) return;
  int begin = indptr[d], end = indptr[d + 1];
  float adst = a_dst[d];
  int e_off = l / 20;
  int pr = l - e_off * 20;
  bool active = (e_off < 3);
  int s0 = __builtin_nontemporal_load(&ssrc[begin]);
  float den = 0.f;
  float acc0 = 0.f, acc1 = 0.f;
  for (int c = begin; c < end; c += 64) {
    int cnt = min(64, end - c);
    int sj = s0;
    float wj = 0.f;
    if (l < cnt) {
      sj = __builtin_nontemporal_load(&ssrc[c + l]);
      float e = a_src[sj] + adst;
      e = (e > 0.f) ? e : 0.2f * e;
      wj = __expf(e);
    }
    den += wj;
    #pragma unroll 4
    for (int j = 0; j < cnt; j += 3) {
      int idx = j + e_off;
      int s = __shfl(sj, idx & 63, 64);
      float wt = __shfl(wj, idx & 63, 64);
      if (!active || idx >= cnt) wt = 0.f;
      ushort2 gv = *(const ushort2*)((const unsigned short*)gb +
                                     (long long)s * C + 2 * pr);
      acc0 += wt * b2f(gv.x);
      acc1 += wt * b2f(gv.y);
    }
  }
  den = wred_sum(den);
  float inv = 1.f / den;
  float r0 = acc0 + __shfl(acc0, (l + 20) & 63, 64) + __shfl(acc0, (l + 40) & 63, 64);
  float r1 = acc1 + __shfl(acc1, (l + 20) & 63, 64) + __shfl(acc1, (l + 40) & 63, 64);
  if (l < 20) {
    float v0 = r0 * inv + ldf(b2, 2 * l + 0, f16);
    float v1 = r1 * inv + ldf(b2, 2 * l + 1, f16);
    long long o = (long long)d * C + 2 * l;
    if (f16) {
      ushort2 ov;
      ov.x = f2bu(v0); ov.y = f2bu(v1);
      *(ushort2*)((unsigned short*)out + o) = ov;
    } else {
      float2 ov;
      ov.x = v0; ov.y = v1;
      *(float2*)((float*)out + o) = ov;
    }
  }
}

extern "C" void kernel_launch(void* const* d_in, const int* in_sizes, int n_in,
                              void* d_out, int out_size, void* d_ws, size_t ws_size,
                              hipStream_t stream) {
  const void* x   = d_in[0];
  const int* edge = (const int*)d_in[1];
  const void* W1  = d_in[2];
  const void* as1 = d_in[3];
  const void* ad1 = d_in[4];
  const void* b1  = d_in[5];
  const void* W2  = d_in[6];
  const void* as2 = d_in[7];
  const void* ad2 = d_in[8];
  const void* b2  = d_in[9];

  const int F  = 256;                 // F_in
  const int HC = 256;                 // H*C1
  const int N  = in_sizes[0] / F;     // 50000
  const int E  = in_sizes[1] / 2;     // 1600000
  const int C2 = in_sizes[9];         // 40
  const int C2p = 64;                 // padded cols for layer-2 B^T
  const int total = E + N;
  const int NB = (N + 255) / 256;     // buckets (196)
  const int Mpad = ((N + 63) / 64) * 64;

  char* p = (char*)d_ws;
  auto alloc = [&](size_t bytes) -> void* {
    void* r = (void*)p;
    p += (bytes + 255) & ~(size_t)255;
    return r;
  };
  __hip_bfloat16* h1b = (__hip_bfloat16*)alloc((size_t)Mpad * HC * 2);
  __hip_bfloat16* h2b = (__hip_bfloat16*)alloc((size_t)Mpad * HC * 2);
  __hip_bfloat16* gb  = (__hip_bfloat16*)alloc((size_t)Mpad * C2 * 2);
  __hip_bfloat16* Wt1 = (__hip_bfloat16*)alloc((size_t)HC * F * 2);
  __hip_bfloat16* Wt2 = (__hip_bfloat16*)alloc((size_t)C2p * HC * 2);
  float* a_src1 = (float*)alloc((size_t)N * 4 * 4);
  float* a_dst1 = (float*)alloc((size_t)N * 4 * 4);
  float* a_src2 = (float*)alloc((size_t)N * 4);
  float* a_dst2 = (float*)alloc((size_t)N * 4);
  unsigned int* part = (unsigned int*)alloc((size_t)total * 4);
  int* bcnt     = (int*)alloc((size_t)(NB + 1) * 4);
  int* bbase    = (int*)alloc((size_t)(NB + 1) * 4);
  int* bcursor  = (int*)alloc((size_t)NB * 4);
  int* indptr   = (int*)alloc((size_t)(N + 1) * 4);
  int* ssrc     = (int*)alloc((size_t)total * 4);
  int* flag     = (int*)alloc(256);

  // ---- detection + CSR build (2-level bucket sort) ----
  hipMemsetAsync(bcnt, 0, (size_t)(NB + 1) * 4, stream);
  detect_kernel<<<1, 256, 0, stream>>>(edge, E < 2048 ? E : 2048,
                                       (const unsigned int*)x, 4096, flag);
  int nch = (total + CHUNK - 1) / CHUNK;
  bucket_count_kernel<<<nch, 256, 0, stream>>>(edge, E, N, flag, bcnt, NB);
  bucket_scan_kernel<<<1, 256, 0, stream>>>(bcnt, NB, bbase, bcursor);
  partition_kernel<<<nch, 256, 0, stream>>>(edge, E, N, flag, bcursor, part, NB);
  bucket_sort_kernel<<<NB, 256, 0, stream>>>(part, bbase, N, total, indptr, ssrc);

  // ---- fused weight transposes ----
  int ntr = HC * F + C2p * HC;
  transpose_both_kernel<<<(ntr + 255) / 256, 256, 0, stream>>>(
      W1, W2, Wt1, Wt2, F, HC, C2, C2p, flag);

  // ---- layer 1: gemm (+fused att, direct A read) -> aggregate ----
  dim3 g1(Mpad / 64, HC / 64);
  mfma_gemm_kernel<true><<<g1, 256, 0, stream>>>(x, Wt1, h1b,
                                                 as1, ad1, a_src1, a_dst1, 4,
                                                 N, HC, F, flag);
  aggregate1_kernel<<<(N + 3) / 4, 256, 0, stream>>>(indptr, ssrc, h1b, a_src1, a_dst1,
                                                     b1, h2b, N, flag);

  // ---- layer 2: gemm (+fused att) -> aggregate ----
  dim3 g2(Mpad / 64, 1);
  mfma_gemm_kernel<false><<<g2, 256, 0, stream>>>(h2b, Wt2, gb,
                                                  as2, ad2, a_src2, a_dst2, 1,
                                                  N, C2, HC, flag);
  aggregate2_kernel<<<(N + 3) / 4, 256, 0, stream>>>(indptr, ssrc, gb, a_src2, a_dst2,
                                                     b2, d_out, N, C2, flag);
}

// Round 11
// 458.168 us; speedup vs baseline: 1.0655x; 1.0061x over previous
//
#include <hip/hip_runtime.h>
#include <hip/hip_bf16.h>

typedef short bf16x8 __attribute__((ext_vector_type(8)));
typedef float f32x4 __attribute__((ext_vector_type(4)));

#define CHUNK 4096

// ---------------- helpers ----------------
__device__ __forceinline__ float wred_sum(float v) {
  #pragma unroll
  for (int off = 32; off > 0; off >>= 1)
    v += __shfl_xor(v, off, 64);
  return v;
}
__device__ __forceinline__ float b2f(unsigned short u) {
  union { unsigned int i; float f; } x;
  x.i = ((unsigned int)u) << 16;
  return x.f;
}
__device__ __forceinline__ unsigned short f2bu(float f) {
  __hip_bfloat16 b = __float2bfloat16(f);
  return *(unsigned short*)&b;
}
// Runtime-dtype float load: is16 ? bf16 : fp32. Wave-uniform flag.
__device__ __forceinline__ float ldf(const void* p, long long i, int is16) {
  return is16 ? __bfloat162float(((const __hip_bfloat16*)p)[i])
              : ((const float*)p)[i];
}
// edge_index may arrive as int32 or int64 (reference declares int64).
__device__ __forceinline__ int edge_at(const int* e, long long idx, int is64) {
  return is64 ? (int)((const long long*)e)[idx] : e[idx];
}

// flag[0] = edge-is-int64, flag[1] = floats-are-bf16
__global__ void detect_kernel(const int* __restrict__ edge, int n_edge_check,
                              const unsigned int* __restrict__ xw, int n_x_check,
                              int* __restrict__ flag) {
  __shared__ int s_nz, s_cnt, s_tot;
  int tid = threadIdx.x;
  if (tid == 0) { s_nz = 0; s_cnt = 0; s_tot = 0; }
  __syncthreads();
  int nz = 0;
  for (int k = tid; k < n_edge_check; k += 256)
    if (edge[2 * k + 1] != 0) nz = 1;
  if (nz) atomicOr(&s_nz, 1);
  // bf16-packed words have bits 14..7 = exponent ~[100,150] for N(0,1) data.
  int c = 0, t = 0;
  for (int k = tid; k < n_x_check; k += 256) {
    unsigned int w = xw[k];
    if (w == 0u) continue;
    t++;
    unsigned int e = (w >> 7) & 0xFFu;
    if (e >= 100u && e <= 150u) c++;
  }
  atomicAdd(&s_cnt, c);
  atomicAdd(&s_tot, t);
  __syncthreads();
  if (tid == 0) {
    flag[0] = (s_nz == 0) ? 1 : 0;
    flag[1] = (s_cnt * 10 > s_tot * 6) ? 1 : 0;
  }
}

// ---------------- CSR build: 2-level bucket sort ----------------
// Bucket b covers dst in [256b, 256b+256). NB = ceil(N/256) <= 1024.
// Payload pack: (dst & 255) << 24 | src   (requires N < 2^24).

__global__ __launch_bounds__(256) void bucket_count_kernel(
    const int* __restrict__ edge, int E, int N, const int* __restrict__ flag,
    int* __restrict__ bcnt, int NB) {
  __shared__ int cnt[1024];
  int tid = threadIdx.x;
  long long base = (long long)blockIdx.x * CHUNK;
  long long total = (long long)E + N;
  for (int b = tid; b < NB; b += 256) cnt[b] = 0;
  __syncthreads();
  int is64 = flag[0];
  #pragma unroll
  for (int j = 0; j < 16; j++) {
    long long i = base + j * 256 + tid;
    if (i < total) {
      int d = (i < E) ? edge_at(edge, (long long)E + i, is64) : (int)(i - E);
      d = min(max(d, 0), N - 1);
      atomicAdd(&cnt[d >> 8], 1);
    }
  }
  __syncthreads();
  for (int b = tid; b < NB; b += 256)
    if (cnt[b]) atomicAdd(&bcnt[b], cnt[b]);
}

__global__ void bucket_scan_kernel(const int* __restrict__ bcnt, int NB,
                                   int* __restrict__ bbase, int* __restrict__ bcursor) {
  __shared__ int s[256];
  __shared__ int rbase;
  int tid = threadIdx.x;
  if (tid == 0) rbase = 0;
  __syncthreads();
  for (int c0 = 0; c0 < NB; c0 += 256) {
    int idx = c0 + tid;
    int v = (idx < NB) ? bcnt[idx] : 0;
    s[tid] = v;
    __syncthreads();
    for (int off = 1; off < 256; off <<= 1) {
      int t = (tid >= off) ? s[tid - off] : 0;
      __syncthreads();
      s[tid] += t;
      __syncthreads();
    }
    int mb = rbase;
    if (idx < NB) {
      int exc = mb + s[tid] - v;
      bbase[idx] = exc;
      bcursor[idx] = exc;
    }
    __syncthreads();
    if (tid == 0) rbase = mb + s[255];
    __syncthreads();
  }
  if (tid == 0) bbase[NB] = rbase;
}

__global__ __launch_bounds__(256) void partition_kernel(
    const int* __restrict__ edge, int E, int N, const int* __restrict__ flag,
    int* __restrict__ bcursor, unsigned int* __restrict__ part, int NB) {
  __shared__ int cnt[1024];
  __shared__ int loff[1025];
  __shared__ int gpos[1024];
  __shared__ int lcur[1024];
  __shared__ unsigned int staged[CHUNK];
  __shared__ int s[256];
  __shared__ int rbase;
  int tid = threadIdx.x;
  long long base = (long long)blockIdx.x * CHUNK;
  long long total = (long long)E + N;
  int here = (int)min((long long)CHUNK, total - base);
  for (int b = tid; b < NB; b += 256) cnt[b] = 0;
  if (tid == 0) rbase = 0;
  __syncthreads();
  int is64 = flag[0];
  int myb[16];
  unsigned int myp[16];
  #pragma unroll
  for (int j = 0; j < 16; j++) {
    long long i = base + j * 256 + tid;
    myb[j] = -1;
    if (i < total) {
      int d, sv;
      if (i < E) {
        sv = edge_at(edge, i, is64);
        d = edge_at(edge, (long long)E + i, is64);
      } else {
        sv = d = (int)(i - E);
      }
      d = min(max(d, 0), N - 1);
      sv = min(max(sv, 0), N - 1);
      myb[j] = d >> 8;
      myp[j] = ((unsigned int)(d & 255) << 24) | (unsigned int)sv;
      atomicAdd(&cnt[myb[j]], 1);
    }
  }
  __syncthreads();
  for (int c0 = 0; c0 < NB; c0 += 256) {
    int idx = c0 + tid;
    int v = (idx < NB) ? cnt[idx] : 0;
    s[tid] = v;
    __syncthreads();
    for (int off = 1; off < 256; off <<= 1) {
      int t = (tid >= off) ? s[tid - off] : 0;
      __syncthreads();
      s[tid] += t;
      __syncthreads();
    }
    int mb = rbase;
    if (idx < NB) loff[idx] = mb + s[tid] - v;
    __syncthreads();
    if (tid == 0) rbase = mb + s[255];
    __syncthreads();
  }
  if (tid == 0) loff[NB] = rbase;  // == here
  __syncthreads();
  for (int b = tid; b < NB; b += 256) {
    int c = cnt[b];
    gpos[b] = c ? atomicAdd(&bcursor[b], c) : 0;
    lcur[b] = loff[b];
  }
  __syncthreads();
  #pragma unroll
  for (int j = 0; j < 16; j++) {
    if (myb[j] >= 0) {
      int slot = atomicAdd(&lcur[myb[j]], 1);
      staged[slot] = myp[j];
    }
  }
  __syncthreads();
  for (int i = tid; i < here; i += 256) {
    int lo = 0, hi = NB;
    while (hi - lo > 1) {
      int mid = (lo + hi) >> 1;
      if (loff[mid] <= i) lo = mid; else hi = mid;
    }
    part[gpos[lo] + (i - loff[lo])] = staged[i];
  }
}

__global__ __launch_bounds__(256) void bucket_sort_kernel(
    const unsigned int* __restrict__ part, const int* __restrict__ bbase,
    int N, int total, int* __restrict__ indptr, int* __restrict__ ssrc) {
  __shared__ int hist[256], cur[256];
  __shared__ int s[256];
  int tid = threadIdx.x;
  int b = blockIdx.x;
  int begin = bbase[b], end = bbase[b + 1];
  hist[tid] = 0;
  __syncthreads();
  for (int i = begin + tid; i < end; i += 256)
    atomicAdd(&hist[part[i] >> 24], 1);
  __syncthreads();
  int v = hist[tid];
  s[tid] = v;
  __syncthreads();
  for (int off = 1; off < 256; off <<= 1) {
    int t = (tid >= off) ? s[tid - off] : 0;
    __syncthreads();
    s[tid] += t;
    __syncthreads();
  }
  int exc = s[tid] - v;
  cur[tid] = exc;
  int d = b * 256 + tid;
  if (d < N) indptr[d] = begin + exc;
  if (b == 0 && tid == 0) indptr[N] = total;
  __syncthreads();
  for (int i = begin + tid; i < end; i += 256) {
    unsigned int p = part[i];
    int pos = begin + atomicAdd(&cur[p >> 24], 1);
    ssrc[pos] = (int)(p & 0xFFFFFFu);
  }
}

// ---------------- dtype convert: flagged float -> padded bf16, 4 elems/thread ----------------
__global__ void convert4_kernel(const void* __restrict__ x, __hip_bfloat16* __restrict__ xb,
                                long long n_valid4, long long n_total4,
                                const int* __restrict__ dflag) {
  long long i = blockIdx.x * 256LL + threadIdx.x;
  if (i >= n_total4) return;
  ushort4 o;
  if (i < n_valid4) {
    if (dflag[1]) {
      o = ((const ushort4*)x)[i];
    } else {
      float4 v = ((const float4*)x)[i];
      o.x = f2bu(v.x); o.y = f2bu(v.y); o.z = f2bu(v.z); o.w = f2bu(v.w);
    }
  } else {
    o.x = o.y = o.z = o.w = 0;
  }
  ((ushort4*)xb)[i] = o;
}

// ---------------- fused weight transposes: W1 and W2 in one dispatch ----------------
__global__ void transpose_both_kernel(const void* __restrict__ W1v,
                                      const void* __restrict__ W2v,
                                      __hip_bfloat16* __restrict__ Wt1,
                                      __hip_bfloat16* __restrict__ Wt2,
                                      int F, int HC, int C2, int C2p,
                                      const int* __restrict__ dflag) {
  int f16 = dflag[1];
  int idx = blockIdx.x * 256 + threadIdx.x;
  int n1 = HC * F;
  if (idx < n1) {
    int n = idx / F, k = idx - n * F;
    Wt1[idx] = __float2bfloat16(ldf(W1v, (long long)k * HC + n, f16));
  } else {
    int j = idx - n1;
    if (j >= C2p * HC) return;
    int n = j / HC, k = j - n * HC;
    float v = (n < C2) ? ldf(W2v, (long long)k * C2 + n, f16) : 0.f;
    Wt2[j] = __float2bfloat16(v);
  }
}

// ---------------- MFMA bf16 GEMM + fused att epilogue ----------------
// block = 256 thr = 4 waves; tile 64x64; wave w owns rows [w*16, w*16+16).
// A [Mpad x K] bf16 (padded rows), BtT [Noutpad x K] bf16, both L2-resident,
// fragments loaded direct from global. mfma_f32_16x16x32_bf16 layouts
// [learn_hip m89/m91]:
//   A[m][k]: m = lane&15, k = (lane>>4)*8 + j ;  B-op from BtT rows likewise.
//   C/D: col = lane&15, row = (lane>>4)*4 + reg
// Epilogue computes a_src/a_dst = C-row . att (16-lane butterfly).
// Output: Cf (fp32) and/or Cb (bf16), nullable.
__global__ __launch_bounds__(256) void mfma_gemm_kernel(
    const __hip_bfloat16* __restrict__ A, const __hip_bfloat16* __restrict__ BtT,
    float* __restrict__ Cf, __hip_bfloat16* __restrict__ Cb,
    const void* __restrict__ attS, const void* __restrict__ attD,
    float* __restrict__ aS, float* __restrict__ aD, int att_stride,
    int M, int Nout, int K, const int* __restrict__ dflag) {
  int f16 = dflag[1];
  int tid = threadIdx.x;
  int w = tid >> 6, l = tid & 63;
  int m_lane = l & 15, q = l >> 4;
  int row0 = blockIdx.x * 64, col0 = blockIdx.y * 64;
  const __hip_bfloat16* Arow = A + (long long)(row0 + w * 16 + m_lane) * K + q * 8;
  const __hip_bfloat16* Brow = BtT + (long long)(col0 + m_lane) * K + q * 8;
  f32x4 acc[4] = {};
  #pragma unroll 4
  for (int k0 = 0; k0 < K; k0 += 32) {
    bf16x8 af = *(const bf16x8*)(Arow + k0);
    #pragma unroll
    for (int t = 0; t < 4; t++) {
      bf16x8 bf = *(const bf16x8*)(Brow + (long long)t * 16 * K + k0);
      acc[t] = __builtin_amdgcn_mfma_f32_16x16x32_bf16(af, bf, acc[t], 0, 0, 0);
    }
  }
  #pragma unroll
  for (int r = 0; r < 4; r++) {
    int gr = row0 + w * 16 + q * 4 + r;
    float ps = 0.f, pd = 0.f;
    #pragma unroll
    for (int t = 0; t < 4; t++) {
      int gc = col0 + t * 16 + m_lane;
      float v = acc[t][r];
      if (gc < Nout) {
        ps += v * ldf(attS, gc, f16);
        pd += v * ldf(attD, gc, f16);
        if (gr < M) {
          if (Cf) Cf[(long long)gr * Nout + gc] = v;
          if (Cb) Cb[(long long)gr * Nout + gc] = __float2bfloat16(v);
        }
      }
    }
    #pragma unroll
    for (int off = 1; off < 16; off <<= 1) {
      ps += __shfl_xor(ps, off, 64);
      pd += __shfl_xor(pd, off, 64);
    }
    if (m_lane == 0 && gr < M) {
      aS[(long long)gr * att_stride + blockIdx.y] = ps;
      aD[(long long)gr * att_stride + blockIdx.y] = pd;
    }
  }
}

// ---------------- layer-1 single-pass softmax + aggregate + bias + ELU ----------------
// (round-7 measured-best form: 1 wave per dst, 32-edge chunks.)
// Wave per dst node. Lane l: head q=l>>4, owns channels 4l..4l+3 (8B load/edge).
// Single pass (no max-shift; |logit|<~20 safe in fp32): unnormalized exp-weighted
// accumulate + denominator together; divide at end.
// NOTE (structural floor, measured r7/r9/r10): FETCH ~405 MB at ~3.6 TB/s
// L2-fill for random 512B gathers from a 25.6 MB table replicated on 8 XCD L2s
// — three parallelism levers (deeper MLP, 2 waves/dst, src-sort) all neutral.
__global__ __launch_bounds__(256) void aggregate1_kernel(
    const int* __restrict__ indptr, const int* __restrict__ ssrc,
    const __hip_bfloat16* __restrict__ h1b, const float* __restrict__ a_src,
    const float* __restrict__ a_dst, const void* __restrict__ b1,
    __hip_bfloat16* __restrict__ h2b, int N, const int* __restrict__ dflag) {
  int f16 = dflag[1];
  int w = threadIdx.x >> 6, l = threadIdx.x & 63;
  int d = blockIdx.x * 4 + w;
  if (d >= N) return;
  int q = l >> 4;
  int e16 = l & 15;
  int base = l & 48;
  int begin = indptr[d], end = indptr[d + 1];
  float adst = a_dst[d * 4 + q];
  int s0 = ssrc[begin];
  float den = 0.f;
  float acc0 = 0.f, acc1 = 0.f, acc2 = 0.f, acc3 = 0.f;
  for (int c = begin; c < end; c += 32) {
    int cnt = end - c;
    int sj0 = s0, sj1 = s0;
    float wj0 = 0.f, wj1 = 0.f;
    if (e16 < cnt) {
      sj0 = ssrc[c + e16];
      float e = a_src[sj0 * 4 + q] + adst;
      e = (e > 0.f) ? e : 0.2f * e;
      wj0 = __expf(e);
    }
    if (e16 + 16 < cnt) {
      sj1 = ssrc[c + e16 + 16];
      float e = a_src[sj1 * 4 + q] + adst;
      e = (e > 0.f) ? e : 0.2f * e;
      wj1 = __expf(e);
    }
    den += wj0 + wj1;
    #pragma unroll
    for (int j = 0; j < 16; j++) {
      int s = __shfl(sj0, base + j, 64);
      float wt = __shfl(wj0, base + j, 64);
      ushort4 hv = *(const ushort4*)((const unsigned short*)h1b +
                                     (long long)s * 256 + 4 * l);
      acc0 += wt * b2f(hv.x);
      acc1 += wt * b2f(hv.y);
      acc2 += wt * b2f(hv.z);
      acc3 += wt * b2f(hv.w);
    }
    #pragma unroll
    for (int j = 0; j < 16; j++) {
      int s = __shfl(sj1, base + j, 64);
      float wt = __shfl(wj1, base + j, 64);
      ushort4 hv = *(const ushort4*)((const unsigned short*)h1b +
                                     (long long)s * 256 + 4 * l);
      acc0 += wt * b2f(hv.x);
      acc1 += wt * b2f(hv.y);
      acc2 += wt * b2f(hv.z);
      acc3 += wt * b2f(hv.w);
    }
  }
  #pragma unroll
  for (int off = 1; off < 16; off <<= 1)
    den += __shfl_xor(den, off, 64);
  float inv = 1.f / den;
  float v0 = acc0 * inv + ldf(b1, 4 * l + 0, f16);
  float v1 = acc1 * inv + ldf(b1, 4 * l + 1, f16);
  float v2 = acc2 * inv + ldf(b1, 4 * l + 2, f16);
  float v3 = acc3 * inv + ldf(b1, 4 * l + 3, f16);
  v0 = (v0 > 0.f) ? v0 : (__expf(v0) - 1.f);
  v1 = (v1 > 0.f) ? v1 : (__expf(v1) - 1.f);
  v2 = (v2 > 0.f) ? v2 : (__expf(v2) - 1.f);
  v3 = (v3 > 0.f) ? v3 : (__expf(v3) - 1.f);
  ushort4 o;
  o.x = f2bu(v0); o.y = f2bu(v1); o.z = f2bu(v2); o.w = f2bu(v3);
  *(ushort4*)((unsigned short*)h2b + (long long)d * 256 + 4 * l) = o;
}

// ---------------- layer-2 single-pass softmax + aggregate + bias -> out ----------------
// Wave per dst; gb fp32 (L2-resident, no per-edge converts). C=40 = 20 pairs;
// lanes split 3 edges x 20 channel-pairs; lane loads float2 (8B).
__global__ __launch_bounds__(256) void aggregate2_kernel(
    const int* __restrict__ indptr, const int* __restrict__ ssrc,
    const float* __restrict__ gf, const float* __restrict__ a_src,
    const float* __restrict__ a_dst, const void* __restrict__ b2,
    void* __restrict__ out, int N, int C, const int* __restrict__ dflag) {
  int f16 = dflag[1];
  int w = threadIdx.x >> 6, l = threadIdx.x & 63;
  int d = blockIdx.x * 4 + w;
  if (d >= N) return;
  int begin = indptr[d], end = indptr[d + 1];
  float adst = a_dst[d];
  int e_off = l / 20;
  int pr = l - e_off * 20;
  bool active = (e_off < 3);
  int s0 = ssrc[begin];
  float den = 0.f;
  float acc0 = 0.f, acc1 = 0.f;
  for (int c = begin; c < end; c += 64) {
    int cnt = min(64, end - c);
    int sj = s0;
    float wj = 0.f;
    if (l < cnt) {
      sj = ssrc[c + l];
      float e = a_src[sj] + adst;
      e = (e > 0.f) ? e : 0.2f * e;
      wj = __expf(e);
    }
    den += wj;
    #pragma unroll 4
    for (int j = 0; j < cnt; j += 3) {
      int idx = j + e_off;
      int s = __shfl(sj, idx & 63, 64);
      float wt = __shfl(wj, idx & 63, 64);
      if (!active || idx >= cnt) wt = 0.f;
      float2 gv = *(const float2*)(gf + (long long)s * C + 2 * pr);
      acc0 += wt * gv.x;
      acc1 += wt * gv.y;
    }
  }
  den = wred_sum(den);
  float inv = 1.f / den;
  float r0 = acc0 + __shfl(acc0, (l + 20) & 63, 64) + __shfl(acc0, (l + 40) & 63, 64);
  float r1 = acc1 + __shfl(acc1, (l + 20) & 63, 64) + __shfl(acc1, (l + 40) & 63, 64);
  if (l < 20) {
    float v0 = r0 * inv + ldf(b2, 2 * l + 0, f16);
    float v1 = r1 * inv + ldf(b2, 2 * l + 1, f16);
    long long o = (long long)d * C + 2 * l;
    if (f16) {
      ushort2 ov;
      ov.x = f2bu(v0); ov.y = f2bu(v1);
      *(ushort2*)((unsigned short*)out + o) = ov;
    } else {
      float2 ov;
      ov.x = v0; ov.y = v1;
      *(float2*)((float*)out + o) = ov;
    }
  }
}

extern "C" void kernel_launch(void* const* d_in, const int* in_sizes, int n_in,
                              void* d_out, int out_size, void* d_ws, size_t ws_size,
                              hipStream_t stream) {
  const void* x   = d_in[0];
  const int* edge = (const int*)d_in[1];
  const void* W1  = d_in[2];
  const void* as1 = d_in[3];
  const void* ad1 = d_in[4];
  const void* b1  = d_in[5];
  const void* W2  = d_in[6];
  const void* as2 = d_in[7];
  const void* ad2 = d_in[8];
  const void* b2  = d_in[9];

  const int F  = 256;                 // F_in
  const int HC = 256;                 // H*C1
  const int N  = in_sizes[0] / F;     // 50000
  const int E  = in_sizes[1] / 2;     // 1600000
  const int C2 = in_sizes[9];         // 40
  const int C2p = 64;                 // padded cols for layer-2 B^T
  const int total = E + N;
  const int NB = (N + 255) / 256;     // buckets (196)
  const int Mpad = ((N + 63) / 64) * 64;

  char* p = (char*)d_ws;
  auto alloc = [&](size_t bytes) -> void* {
    void* r = (void*)p;
    p += (bytes + 255) & ~(size_t)255;
    return r;
  };
  __hip_bfloat16* xb  = (__hip_bfloat16*)alloc((size_t)Mpad * F * 2);
  __hip_bfloat16* h1b = (__hip_bfloat16*)alloc((size_t)Mpad * HC * 2);
  __hip_bfloat16* h2b = (__hip_bfloat16*)alloc((size_t)Mpad * HC * 2);
  float* gf     = (float*)alloc((size_t)Mpad * C2 * 4);
  __hip_bfloat16* Wt1 = (__hip_bfloat16*)alloc((size_t)HC * F * 2);
  __hip_bfloat16* Wt2 = (__hip_bfloat16*)alloc((size_t)C2p * HC * 2);
  float* a_src1 = (float*)alloc((size_t)N * 4 * 4);
  float* a_dst1 = (float*)alloc((size_t)N * 4 * 4);
  float* a_src2 = (float*)alloc((size_t)N * 4);
  float* a_dst2 = (float*)alloc((size_t)N * 4);
  unsigned int* part = (unsigned int*)alloc((size_t)total * 4);
  int* bcnt     = (int*)alloc((size_t)(NB + 1) * 4);
  int* bbase    = (int*)alloc((size_t)(NB + 1) * 4);
  int* bcursor  = (int*)alloc((size_t)NB * 4);
  int* indptr   = (int*)alloc((size_t)(N + 1) * 4);
  int* ssrc     = (int*)alloc((size_t)total * 4);
  int* flag     = (int*)alloc(256);

  // ---- detection + CSR build (2-level bucket sort) ----
  hipMemsetAsync(bcnt, 0, (size_t)(NB + 1) * 4, stream);
  detect_kernel<<<1, 256, 0, stream>>>(edge, E < 2048 ? E : 2048,
                                       (const unsigned int*)x, 4096, flag);
  int nch = (total + CHUNK - 1) / CHUNK;
  bucket_count_kernel<<<nch, 256, 0, stream>>>(edge, E, N, flag, bcnt, NB);
  bucket_scan_kernel<<<1, 256, 0, stream>>>(bcnt, NB, bbase, bcursor);
  partition_kernel<<<nch, 256, 0, stream>>>(edge, E, N, flag, bcursor, part, NB);
  bucket_sort_kernel<<<NB, 256, 0, stream>>>(part, bbase, N, total, indptr, ssrc);

  // ---- fused weight transposes + input convert ----
  int ntr = HC * F + C2p * HC;
  transpose_both_kernel<<<(ntr + 255) / 256, 256, 0, stream>>>(
      W1, W2, Wt1, Wt2, F, HC, C2, C2p, flag);
  long long nconv4 = (long long)Mpad * F / 4;
  convert4_kernel<<<(int)((nconv4 + 255) / 256), 256, 0, stream>>>(
      x, xb, (long long)N * F / 4, nconv4, flag);

  // ---- layer 1: gemm (+fused att) -> aggregate ----
  dim3 g1(Mpad / 64, HC / 64);
  mfma_gemm_kernel<<<g1, 256, 0, stream>>>(xb, Wt1, nullptr, h1b,
                                           as1, ad1, a_src1, a_dst1, 4,
                                           N, HC, F, flag);
  aggregate1_kernel<<<(N + 3) / 4, 256, 0, stream>>>(indptr, ssrc, h1b, a_src1, a_dst1,
                                                     b1, h2b, N, flag);

  // ---- layer 2: gemm (+fused att, fp32 out) -> aggregate ----
  dim3 g2(Mpad / 64, 1);
  mfma_gemm_kernel<<<g2, 256, 0, stream>>>(h2b, Wt2, gf, nullptr,
                                           as2, ad2, a_src2, a_dst2, 1,
                                           N, C2, HC, flag);
  aggregate2_kernel<<<(N + 3) / 4, 256, 0, stream>>>(indptr, ssrc, gf, a_src2, a_dst2,
                                                     b2, d_out, N, C2, flag);
}

// Round 12
// 442.191 us; speedup vs baseline: 1.1040x; 1.0361x over previous
//
#include <hip/hip_runtime.h>
#include <hip/hip_bf16.h>

typedef short bf16x8 __attribute__((ext_vector_type(8)));
typedef float f32x4 __attribute__((ext_vector_type(4)));

#define CHUNK 4096

// ---------------- helpers ----------------
__device__ __forceinline__ float wred_sum(float v) {
  #pragma unroll
  for (int off = 32; off > 0; off >>= 1)
    v += __shfl_xor(v, off, 64);
  return v;
}
__device__ __forceinline__ float b2f(unsigned short u) {
  union { unsigned int i; float f; } x;
  x.i = ((unsigned int)u) << 16;
  return x.f;
}
__device__ __forceinline__ unsigned short f2bu(float f) {
  __hip_bfloat16 b = __float2bfloat16(f);
  return *(unsigned short*)&b;
}
// Runtime-dtype float load: is16 ? bf16 : fp32. Wave-uniform flag.
__device__ __forceinline__ float ldf(const void* p, long long i, int is16) {
  return is16 ? __bfloat162float(((const __hip_bfloat16*)p)[i])
              : ((const float*)p)[i];
}
// edge_index may arrive as int32 or int64 (reference declares int64).
__device__ __forceinline__ int edge_at(const int* e, long long idx, int is64) {
  return is64 ? (int)((const long long*)e)[idx] : e[idx];
}

// flag[0] = edge-is-int64, flag[1] = floats-are-bf16
__global__ void detect_kernel(const int* __restrict__ edge, int n_edge_check,
                              const unsigned int* __restrict__ xw, int n_x_check,
                              int* __restrict__ flag) {
  __shared__ int s_nz, s_cnt, s_tot;
  int tid = threadIdx.x;
  if (tid == 0) { s_nz = 0; s_cnt = 0; s_tot = 0; }
  __syncthreads();
  int nz = 0;
  for (int k = tid; k < n_edge_check; k += 256)
    if (edge[2 * k + 1] != 0) nz = 1;
  if (nz) atomicOr(&s_nz, 1);
  // bf16-packed words have bits 14..7 = exponent ~[100,150] for N(0,1) data.
  int c = 0, t = 0;
  for (int k = tid; k < n_x_check; k += 256) {
    unsigned int w = xw[k];
    if (w == 0u) continue;
    t++;
    unsigned int e = (w >> 7) & 0xFFu;
    if (e >= 100u && e <= 150u) c++;
  }
  atomicAdd(&s_cnt, c);
  atomicAdd(&s_tot, t);
  __syncthreads();
  if (tid == 0) {
    flag[0] = (s_nz == 0) ? 1 : 0;
    flag[1] = (s_cnt * 10 > s_tot * 6) ? 1 : 0;
  }
}

// ---------------- CSR build: 2-level bucket sort ----------------
// Bucket b covers dst in [256b, 256b+256). NB = ceil(N/256) <= 1024.
// Payload pack: (dst & 255) << 24 | src   (requires N < 2^24).

__global__ __launch_bounds__(256) void bucket_count_kernel(
    const int* __restrict__ edge, int E, int N, const int* __restrict__ flag,
    int* __restrict__ bcnt, int NB) {
  __shared__ int cnt[1024];
  int tid = threadIdx.x;
  long long base = (long long)blockIdx.x * CHUNK;
  long long total = (long long)E + N;
  for (int b = tid; b < NB; b += 256) cnt[b] = 0;
  __syncthreads();
  int is64 = flag[0];
  #pragma unroll
  for (int j = 0; j < 16; j++) {
    long long i = base + j * 256 + tid;
    if (i < total) {
      int d = (i < E) ? edge_at(edge, (long long)E + i, is64) : (int)(i - E);
      d = min(max(d, 0), N - 1);
      atomicAdd(&cnt[d >> 8], 1);
    }
  }
  __syncthreads();
  for (int b = tid; b < NB; b += 256)
    if (cnt[b]) atomicAdd(&bcnt[b], cnt[b]);
}

__global__ void bucket_scan_kernel(const int* __restrict__ bcnt, int NB,
                                   int* __restrict__ bbase, int* __restrict__ bcursor) {
  __shared__ int s[256];
  __shared__ int rbase;
  int tid = threadIdx.x;
  if (tid == 0) rbase = 0;
  __syncthreads();
  for (int c0 = 0; c0 < NB; c0 += 256) {
    int idx = c0 + tid;
    int v = (idx < NB) ? bcnt[idx] : 0;
    s[tid] = v;
    __syncthreads();
    for (int off = 1; off < 256; off <<= 1) {
      int t = (tid >= off) ? s[tid - off] : 0;
      __syncthreads();
      s[tid] += t;
      __syncthreads();
    }
    int mb = rbase;
    if (idx < NB) {
      int exc = mb + s[tid] - v;
      bbase[idx] = exc;
      bcursor[idx] = exc;
    }
    __syncthreads();
    if (tid == 0) rbase = mb + s[255];
    __syncthreads();
  }
  if (tid == 0) bbase[NB] = rbase;
}

// Partition with precomputed flush addresses: at staging time bucket b's global
// base (gpos) and local offset (slot - loff) are both known, so the flush loop
// needs no per-edge binary search (2 LDS reads + 1 store per edge).
__global__ __launch_bounds__(256) void partition_kernel(
    const int* __restrict__ edge, int E, int N, const int* __restrict__ flag,
    int* __restrict__ bcursor, unsigned int* __restrict__ part, int NB) {
  __shared__ int cnt[1024];
  __shared__ int loff[1025];
  __shared__ int gpos[1024];
  __shared__ int lcur[1024];
  __shared__ unsigned int staged[CHUNK];
  __shared__ int staged_addr[CHUNK];
  __shared__ int s[256];
  __shared__ int rbase;
  int tid = threadIdx.x;
  long long base = (long long)blockIdx.x * CHUNK;
  long long total = (long long)E + N;
  int here = (int)min((long long)CHUNK, total - base);
  for (int b = tid; b < NB; b += 256) cnt[b] = 0;
  if (tid == 0) rbase = 0;
  __syncthreads();
  int is64 = flag[0];
  int myb[16];
  unsigned int myp[16];
  #pragma unroll
  for (int j = 0; j < 16; j++) {
    long long i = base + j * 256 + tid;
    myb[j] = -1;
    if (i < total) {
      int d, sv;
      if (i < E) {
        sv = edge_at(edge, i, is64);
        d = edge_at(edge, (long long)E + i, is64);
      } else {
        sv = d = (int)(i - E);
      }
      d = min(max(d, 0), N - 1);
      sv = min(max(sv, 0), N - 1);
      myb[j] = d >> 8;
      myp[j] = ((unsigned int)(d & 255) << 24) | (unsigned int)sv;
      atomicAdd(&cnt[myb[j]], 1);
    }
  }
  __syncthreads();
  for (int c0 = 0; c0 < NB; c0 += 256) {
    int idx = c0 + tid;
    int v = (idx < NB) ? cnt[idx] : 0;
    s[tid] = v;
    __syncthreads();
    for (int off = 1; off < 256; off <<= 1) {
      int t = (tid >= off) ? s[tid - off] : 0;
      __syncthreads();
      s[tid] += t;
      __syncthreads();
    }
    int mb = rbase;
    if (idx < NB) loff[idx] = mb + s[tid] - v;
    __syncthreads();
    if (tid == 0) rbase = mb + s[255];
    __syncthreads();
  }
  __syncthreads();
  for (int b = tid; b < NB; b += 256) {
    int c = cnt[b];
    gpos[b] = c ? atomicAdd(&bcursor[b], c) : 0;
    lcur[b] = loff[b];
  }
  __syncthreads();
  #pragma unroll
  for (int j = 0; j < 16; j++) {
    if (myb[j] >= 0) {
      int b = myb[j];
      int slot = atomicAdd(&lcur[b], 1);
      staged[slot] = myp[j];
      staged_addr[slot] = gpos[b] + (slot - loff[b]);
    }
  }
  __syncthreads();
  for (int i = tid; i < here; i += 256)
    part[staged_addr[i]] = staged[i];
}

__global__ __launch_bounds__(256) void bucket_sort_kernel(
    const unsigned int* __restrict__ part, const int* __restrict__ bbase,
    int N, int total, int* __restrict__ indptr, int* __restrict__ ssrc) {
  __shared__ int hist[256], cur[256];
  __shared__ int s[256];
  int tid = threadIdx.x;
  int b = blockIdx.x;
  int begin = bbase[b], end = bbase[b + 1];
  hist[tid] = 0;
  __syncthreads();
  for (int i = begin + tid; i < end; i += 256)
    atomicAdd(&hist[part[i] >> 24], 1);
  __syncthreads();
  int v = hist[tid];
  s[tid] = v;
  __syncthreads();
  for (int off = 1; off < 256; off <<= 1) {
    int t = (tid >= off) ? s[tid - off] : 0;
    __syncthreads();
    s[tid] += t;
    __syncthreads();
  }
  int exc = s[tid] - v;
  cur[tid] = exc;
  int d = b * 256 + tid;
  if (d < N) indptr[d] = begin + exc;
  if (b == 0 && tid == 0) indptr[N] = total;
  __syncthreads();
  for (int i = begin + tid; i < end; i += 256) {
    unsigned int p = part[i];
    int pos = begin + atomicAdd(&cur[p >> 24], 1);
    ssrc[pos] = (int)(p & 0xFFFFFFu);
  }
}

// ---------------- fused prep: x convert (vec4) + W1/W2 transposes ----------------
// Region 0: i < nconv4           -> xb[4i..4i+3] = bf16(x[4i..4i+3]) (0-pad rows)
// Region 1: HC*F elements        -> Wt1[n][k] = W1[k][n]
// Region 2: C2p*HC elements      -> Wt2[n][k] = W2[k][n] (col-padded to C2p)
__global__ void prep_kernel(const void* __restrict__ x, __hip_bfloat16* __restrict__ xb,
                            long long n_valid4, long long nconv4,
                            const void* __restrict__ W1v, const void* __restrict__ W2v,
                            __hip_bfloat16* __restrict__ Wt1, __hip_bfloat16* __restrict__ Wt2,
                            int F, int HC, int C2, int C2p,
                            const int* __restrict__ dflag) {
  int f16 = dflag[1];
  long long i = blockIdx.x * 256LL + threadIdx.x;
  if (i < nconv4) {
    ushort4 o;
    if (i < n_valid4) {
      if (f16) {
        o = ((const ushort4*)x)[i];
      } else {
        float4 v = ((const float4*)x)[i];
        o.x = f2bu(v.x); o.y = f2bu(v.y); o.z = f2bu(v.z); o.w = f2bu(v.w);
      }
    } else {
      o.x = o.y = o.z = o.w = 0;
    }
    ((ushort4*)xb)[i] = o;
    return;
  }
  long long j = i - nconv4;
  int n1 = HC * F;
  if (j < n1) {
    int idx = (int)j;
    int n = idx / F, k = idx - n * F;
    Wt1[idx] = __float2bfloat16(ldf(W1v, (long long)k * HC + n, f16));
  } else {
    int jj = (int)(j - n1);
    if (jj >= C2p * HC) return;
    int n = jj / HC, k = jj - n * HC;
    float v = (n < C2) ? ldf(W2v, (long long)k * C2 + n, f16) : 0.f;
    Wt2[jj] = __float2bfloat16(v);
  }
}

// ---------------- MFMA bf16 GEMM + fused att epilogue ----------------
// block = 256 thr = 4 waves; tile 64x64; wave w owns rows [w*16, w*16+16).
// A [Mpad x K] bf16 (padded rows), BtT [Noutpad x K] bf16, both L2-resident,
// fragments loaded direct from global. mfma_f32_16x16x32_bf16 layouts
// [learn_hip m89/m91]:
//   A[m][k]: m = lane&15, k = (lane>>4)*8 + j ;  B-op from BtT rows likewise.
//   C/D: col = lane&15, row = (lane>>4)*4 + reg
// Epilogue computes a_src/a_dst = C-row . att (16-lane butterfly).
__global__ __launch_bounds__(256) void mfma_gemm_kernel(
    const __hip_bfloat16* __restrict__ A, const __hip_bfloat16* __restrict__ BtT,
    __hip_bfloat16* __restrict__ Cb,
    const void* __restrict__ attS, const void* __restrict__ attD,
    float* __restrict__ aS, float* __restrict__ aD, int att_stride,
    int M, int Nout, int K, const int* __restrict__ dflag) {
  int f16 = dflag[1];
  int tid = threadIdx.x;
  int w = tid >> 6, l = tid & 63;
  int m_lane = l & 15, q = l >> 4;
  int row0 = blockIdx.x * 64, col0 = blockIdx.y * 64;
  const __hip_bfloat16* Arow = A + (long long)(row0 + w * 16 + m_lane) * K + q * 8;
  const __hip_bfloat16* Brow = BtT + (long long)(col0 + m_lane) * K + q * 8;
  f32x4 acc[4] = {};
  #pragma unroll 4
  for (int k0 = 0; k0 < K; k0 += 32) {
    bf16x8 af = *(const bf16x8*)(Arow + k0);
    #pragma unroll
    for (int t = 0; t < 4; t++) {
      bf16x8 bf = *(const bf16x8*)(Brow + (long long)t * 16 * K + k0);
      acc[t] = __builtin_amdgcn_mfma_f32_16x16x32_bf16(af, bf, acc[t], 0, 0, 0);
    }
  }
  #pragma unroll
  for (int r = 0; r < 4; r++) {
    int gr = row0 + w * 16 + q * 4 + r;
    float ps = 0.f, pd = 0.f;
    #pragma unroll
    for (int t = 0; t < 4; t++) {
      int gc = col0 + t * 16 + m_lane;
      float v = acc[t][r];
      if (gc < Nout) {
        ps += v * ldf(attS, gc, f16);
        pd += v * ldf(attD, gc, f16);
        if (gr < M) Cb[(long long)gr * Nout + gc] = __float2bfloat16(v);
      }
    }
    #pragma unroll
    for (int off = 1; off < 16; off <<= 1) {
      ps += __shfl_xor(ps, off, 64);
      pd += __shfl_xor(pd, off, 64);
    }
    if (m_lane == 0 && gr < M) {
      aS[(long long)gr * att_stride + blockIdx.y] = ps;
      aD[(long long)gr * att_stride + blockIdx.y] = pd;
    }
  }
}

// ---------------- layer-1 single-pass softmax + aggregate + bias + ELU ----------------
// (round-7 measured-best form: 1 wave per dst, 32-edge chunks.)
// Wave per dst node. Lane l: head q=l>>4, owns channels 4l..4l+3 (8B load/edge).
// Single pass (no max-shift; |logit|<~20 safe in fp32): unnormalized exp-weighted
// accumulate + denominator together; divide at end.
// NOTE (structural floor, measured r7/r9/r10/r11): FETCH ~405 MB at ~3.6 TB/s
// L2-fill for random 512B gathers from a 25.6 MB table replicated on 8 XCD L2s
// — deeper MLP, 2 waves/dst, and src-sort all measured neutral.
__global__ __launch_bounds__(256) void aggregate1_kernel(
    const int* __restrict__ indptr, const int* __restrict__ ssrc,
    const __hip_bfloat16* __restrict__ h1b, const float* __restrict__ a_src,
    const float* __restrict__ a_dst, const void* __restrict__ b1,
    __hip_bfloat16* __restrict__ h2b, int N, const int* __restrict__ dflag) {
  int f16 = dflag[1];
  int w = threadIdx.x >> 6, l = threadIdx.x & 63;
  int d = blockIdx.x * 4 + w;
  if (d >= N) return;
  int q = l >> 4;
  int e16 = l & 15;
  int base = l & 48;
  int begin = indptr[d], end = indptr[d + 1];
  float adst = a_dst[d * 4 + q];
  int s0 = ssrc[begin];
  float den = 0.f;
  float acc0 = 0.f, acc1 = 0.f, acc2 = 0.f, acc3 = 0.f;
  for (int c = begin; c < end; c += 32) {
    int cnt = end - c;
    int sj0 = s0, sj1 = s0;
    float wj0 = 0.f, wj1 = 0.f;
    if (e16 < cnt) {
      sj0 = ssrc[c + e16];
      float e = a_src[sj0 * 4 + q] + adst;
      e = (e > 0.f) ? e : 0.2f * e;
      wj0 = __expf(e);
    }
    if (e16 + 16 < cnt) {
      sj1 = ssrc[c + e16 + 16];
      float e = a_src[sj1 * 4 + q] + adst;
      e = (e > 0.f) ? e : 0.2f * e;
      wj1 = __expf(e);
    }
    den += wj0 + wj1;
    #pragma unroll
    for (int j = 0; j < 16; j++) {
      int s = __shfl(sj0, base + j, 64);
      float wt = __shfl(wj0, base + j, 64);
      ushort4 hv = *(const ushort4*)((const unsigned short*)h1b +
                                     (long long)s * 256 + 4 * l);
      acc0 += wt * b2f(hv.x);
      acc1 += wt * b2f(hv.y);
      acc2 += wt * b2f(hv.z);
      acc3 += wt * b2f(hv.w);
    }
    #pragma unroll
    for (int j = 0; j < 16; j++) {
      int s = __shfl(sj1, base + j, 64);
      float wt = __shfl(wj1, base + j, 64);
      ushort4 hv = *(const ushort4*)((const unsigned short*)h1b +
                                     (long long)s * 256 + 4 * l);
      acc0 += wt * b2f(hv.x);
      acc1 += wt * b2f(hv.y);
      acc2 += wt * b2f(hv.z);
      acc3 += wt * b2f(hv.w);
    }
  }
  #pragma unroll
  for (int off = 1; off < 16; off <<= 1)
    den += __shfl_xor(den, off, 64);
  float inv = 1.f / den;
  float v0 = acc0 * inv + ldf(b1, 4 * l + 0, f16);
  float v1 = acc1 * inv + ldf(b1, 4 * l + 1, f16);
  float v2 = acc2 * inv + ldf(b1, 4 * l + 2, f16);
  float v3 = acc3 * inv + ldf(b1, 4 * l + 3, f16);
  v0 = (v0 > 0.f) ? v0 : (__expf(v0) - 1.f);
  v1 = (v1 > 0.f) ? v1 : (__expf(v1) - 1.f);
  v2 = (v2 > 0.f) ? v2 : (__expf(v2) - 1.f);
  v3 = (v3 > 0.f) ? v3 : (__expf(v3) - 1.f);
  ushort4 o;
  o.x = f2bu(v0); o.y = f2bu(v1); o.z = f2bu(v2); o.w = f2bu(v3);
  *(ushort4*)((unsigned short*)h2b + (long long)d * 256 + 4 * l) = o;
}

// ---------------- layer-2 single-pass softmax + aggregate + bias -> out ----------------
// (round-7 measured-best form: 1 wave per dst, bf16 gb — fp32 gb doubled the
// per-edge L2 bytes and regressed, r11.) C=40 bf16 = 20 pairs; lanes split
// 3 edges x 20 channel-pairs.
__global__ __launch_bounds__(256) void aggregate2_kernel(
    const int* __restrict__ indptr, const int* __restrict__ ssrc,
    const __hip_bfloat16* __restrict__ gb, const float* __restrict__ a_src,
    const float* __restrict__ a_dst, const void* __restrict__ b2,
    void* __restrict__ out, int N, int C, const int* __restrict__ dflag) {
  int f16 = dflag[1];
  int w = threadIdx.x >> 6, l = threadIdx.x & 63;
  int d = blockIdx.x * 4 + w;
  if (d >= N) return;
  int begin = indptr[d], end = indptr[d + 1];
  float adst = a_dst[d];
  int e_off = l / 20;
  int pr = l - e_off * 20;
  bool active = (e_off < 3);
  int s0 = ssrc[begin];
  float den = 0.f;
  float acc0 = 0.f, acc1 = 0.f;
  for (int c = begin; c < end; c += 64) {
    int cnt = min(64, end - c);
    int sj = s0;
    float wj = 0.f;
    if (l < cnt) {
      sj = ssrc[c + l];
      float e = a_src[sj] + adst;
      e = (e > 0.f) ? e : 0.2f * e;
      wj = __expf(e);
    }
    den += wj;
    #pragma unroll 4
    for (int j = 0; j < cnt; j += 3) {
      int idx = j + e_off;
      int s = __shfl(sj, idx & 63, 64);
      float wt = __shfl(wj, idx & 63, 64);
      if (!active || idx >= cnt) wt = 0.f;
      ushort2 gv = *(const ushort2*)((const unsigned short*)gb +
                                     (long long)s * C + 2 * pr);
      acc0 += wt * b2f(gv.x);
      acc1 += wt * b2f(gv.y);
    }
  }
  den = wred_sum(den);
  float inv = 1.f / den;
  float r0 = acc0 + __shfl(acc0, (l + 20) & 63, 64) + __shfl(acc0, (l + 40) & 63, 64);
  float r1 = acc1 + __shfl(acc1, (l + 20) & 63, 64) + __shfl(acc1, (l + 40) & 63, 64);
  if (l < 20) {
    float v0 = r0 * inv + ldf(b2, 2 * l + 0, f16);
    float v1 = r1 * inv + ldf(b2, 2 * l + 1, f16);
    long long o = (long long)d * C + 2 * l;
    if (f16) {
      ushort2 ov;
      ov.x = f2bu(v0); ov.y = f2bu(v1);
      *(ushort2*)((unsigned short*)out + o) = ov;
    } else {
      float2 ov;
      ov.x = v0; ov.y = v1;
      *(float2*)((float*)out + o) = ov;
    }
  }
}

extern "C" void kernel_launch(void* const* d_in, const int* in_sizes, int n_in,
                              void* d_out, int out_size, void* d_ws, size_t ws_size,
                              hipStream_t stream) {
  const void* x   = d_in[0];
  const int* edge = (const int*)d_in[1];
  const void* W1  = d_in[2];
  const void* as1 = d_in[3];
  const void* ad1 = d_in[4];
  const void* b1  = d_in[5];
  const void* W2  = d_in[6];
  const void* as2 = d_in[7];
  const void* ad2 = d_in[8];
  const void* b2  = d_in[9];

  const int F  = 256;                 // F_in
  const int HC = 256;                 // H*C1
  const int N  = in_sizes[0] / F;     // 50000
  const int E  = in_sizes[1] / 2;     // 1600000
  const int C2 = in_sizes[9];         // 40
  const int C2p = 64;                 // padded cols for layer-2 B^T
  const int total = E + N;
  const int NB = (N + 255) / 256;     // buckets (196)
  const int Mpad = ((N + 63) / 64) * 64;

  char* p = (char*)d_ws;
  auto alloc = [&](size_t bytes) -> void* {
    void* r = (void*)p;
    p += (bytes + 255) & ~(size_t)255;
    return r;
  };
  __hip_bfloat16* xb  = (__hip_bfloat16*)alloc((size_t)Mpad * F * 2);
  __hip_bfloat16* h1b = (__hip_bfloat16*)alloc((size_t)Mpad * HC * 2);
  __hip_bfloat16* h2b = (__hip_bfloat16*)alloc((size_t)Mpad * HC * 2);
  __hip_bfloat16* gb  = (__hip_bfloat16*)alloc((size_t)Mpad * C2 * 2);
  __hip_bfloat16* Wt1 = (__hip_bfloat16*)alloc((size_t)HC * F * 2);
  __hip_bfloat16* Wt2 = (__hip_bfloat16*)alloc((size_t)C2p * HC * 2);
  float* a_src1 = (float*)alloc((size_t)N * 4 * 4);
  float* a_dst1 = (float*)alloc((size_t)N * 4 * 4);
  float* a_src2 = (float*)alloc((size_t)N * 4);
  float* a_dst2 = (float*)alloc((size_t)N * 4);
  unsigned int* part = (unsigned int*)alloc((size_t)total * 4);
  int* bcnt     = (int*)alloc((size_t)(NB + 1) * 4);
  int* bbase    = (int*)alloc((size_t)(NB + 1) * 4);
  int* bcursor  = (int*)alloc((size_t)NB * 4);
  int* indptr   = (int*)alloc((size_t)(N + 1) * 4);
  int* ssrc     = (int*)alloc((size_t)total * 4);
  int* flag     = (int*)alloc(256);

  // ---- detection + CSR build (2-level bucket sort) ----
  hipMemsetAsync(bcnt, 0, (size_t)(NB + 1) * 4, stream);
  detect_kernel<<<1, 256, 0, stream>>>(edge, E < 2048 ? E : 2048,
                                       (const unsigned int*)x, 4096, flag);
  int nch = (total + CHUNK - 1) / CHUNK;
  bucket_count_kernel<<<nch, 256, 0, stream>>>(edge, E, N, flag, bcnt, NB);
  bucket_scan_kernel<<<1, 256, 0, stream>>>(bcnt, NB, bbase, bcursor);
  partition_kernel<<<nch, 256, 0, stream>>>(edge, E, N, flag, bcursor, part, NB);
  bucket_sort_kernel<<<NB, 256, 0, stream>>>(part, bbase, N, total, indptr, ssrc);

  // ---- fused prep: x convert + W1/W2 transposes ----
  long long nconv4 = (long long)Mpad * F / 4;
  long long nprep = nconv4 + (long long)HC * F + (long long)C2p * HC;
  prep_kernel<<<(int)((nprep + 255) / 256), 256, 0, stream>>>(
      x, xb, (long long)N * F / 4, nconv4, W1, W2, Wt1, Wt2, F, HC, C2, C2p, flag);

  // ---- layer 1: gemm (+fused att) -> aggregate ----
  dim3 g1(Mpad / 64, HC / 64);
  mfma_gemm_kernel<<<g1, 256, 0, stream>>>(xb, Wt1, h1b,
                                           as1, ad1, a_src1, a_dst1, 4,
                                           N, HC, F, flag);
  aggregate1_kernel<<<(N + 3) / 4, 256, 0, stream>>>(indptr, ssrc, h1b, a_src1, a_dst1,
                                                     b1, h2b, N, flag);

  // ---- layer 2: gemm (+fused att) -> aggregate ----
  dim3 g2(Mpad / 64, 1);
  mfma_gemm_kernel<<<g2, 256, 0, stream>>>(h2b, Wt2, gb,
                                           as2, ad2, a_src2, a_dst2, 1,
                                           N, C2, HC, flag);
  aggregate2_kernel<<<(N + 3) / 4, 256, 0, stream>>>(indptr, ssrc, gb, a_src2, a_dst2,
                                                     b2, d_out, N, C2, flag);
}